// Round 1
// baseline (1190.735 us; speedup 1.0000x reference)
//
#include <hip/hip_runtime.h>

#define D_   256
#define UD_  48
#define NO_  80
#define T_   128
#define B_   2048

typedef __bf16 bf16x8 __attribute__((ext_vector_type(8)));
typedef float  f32x4  __attribute__((ext_vector_type(4)));
typedef unsigned short ushort_t;

static __device__ __forceinline__ ushort_t f2bf(float f){
  return __builtin_bit_cast(ushort_t, (__bf16)f);
}
static __device__ __forceinline__ float bf2f(ushort_t u){
  union { unsigned int i; float f; } c; c.i = ((unsigned int)u) << 16; return c.f;
}
static __device__ __forceinline__ f32x4 mfma16(bf16x8 a, bf16x8 b, f32x4 c){
  return __builtin_amdgcn_mfma_f32_16x16x32_bf16(a, b, c, 0, 0, 0);
}

// ---------------- prep ----------------

__global__ void k_init(const float* __restrict__ V, const float* __restrict__ eig,
                       float* __restrict__ Xa, float* __restrict__ lam){
  const int i = blockIdx.x, j = threadIdx.x;
  Xa[i*D_ + j] = (i == j ? 2.0f : 0.0f) - V[i*D_ + j];
  if (j == 0) lam[i] = 0.99f / (1.0f + expf(-eig[i]));
}

__global__ void k_mm_mul(const float* __restrict__ A, const float* __restrict__ B,
                         float* __restrict__ Cm){
  const int i = blockIdx.x, j = threadIdx.x;
  const float* Ar = A + i*D_;
  float a0=0.f,a1=0.f,a2=0.f,a3=0.f;
  #pragma unroll 4
  for (int k = 0; k < D_; k += 4){
    a0 += Ar[k+0] * B[(k+0)*D_ + j];
    a1 += Ar[k+1] * B[(k+1)*D_ + j];
    a2 += Ar[k+2] * B[(k+2)*D_ + j];
    a3 += Ar[k+3] * B[(k+3)*D_ + j];
  }
  Cm[i*D_ + j] = (a0+a1)+(a2+a3);
}

__global__ void k_mm_upd(const float* __restrict__ X, const float* __restrict__ Tm,
                         float* __restrict__ Xn){
  const int i = blockIdx.x, j = threadIdx.x;
  const float* Xr = X + i*D_;
  float a0=0.f,a1=0.f,a2=0.f,a3=0.f;
  #pragma unroll 4
  for (int k = 0; k < D_; k += 4){
    a0 += Xr[k+0] * Tm[(k+0)*D_ + j];
    a1 += Xr[k+1] * Tm[(k+1)*D_ + j];
    a2 += Xr[k+2] * Tm[(k+2)*D_ + j];
    a3 += Xr[k+3] * Tm[(k+3)*D_ + j];
  }
  Xn[i*D_ + j] = 2.0f*Xr[j] - ((a0+a1)+(a2+a3));
}

// VinvT = Vinv^T (+dVd); Lw = dt * Vinv @ L; Cw = C @ V
__global__ void k_prep1(const float* __restrict__ Vinv, const float* __restrict__ V,
                        const float* __restrict__ Lm, const float* __restrict__ Cmat,
                        const float* __restrict__ dt,
                        float* __restrict__ VinvT, float* __restrict__ Lw,
                        float* __restrict__ Cw, float* __restrict__ dVd){
  const int bid = blockIdx.x, tid = threadIdx.x;
  if (bid < 256){
    VinvT[tid*D_ + bid] = Vinv[bid*D_ + tid];
    if (tid == bid){ float v = V[bid*D_ + bid]; dVd[bid] = v - bf2f(f2bf(v)); }
  } else if (bid < 512){
    const int i = bid - 256;
    if (tid < UD_){
      float acc = 0.f;
      #pragma unroll 4
      for (int j = 0; j < D_; ++j) acc += Vinv[i*D_ + j] * Lm[j*UD_ + tid];
      Lw[i*UD_ + tid] = acc * dt[0];
    }
  } else {
    const int n = bid - 512;
    float acc = 0.f;
    #pragma unroll 4
    for (int j = 0; j < D_; ++j) acc += Cmat[n*D_ + j] * V[j*D_ + tid];
    Cw[n*D_ + tid] = acc;
  }
}

// w0 = z0 @ VinvT -> Wchk[0] (bf16), 8 rows/block; pack Lws A-fragments.
// k-map (bijective, A/B consistent): k = 32*kc + 4*lh + (j&3) + 16*(j>>2)
__global__ void k_prep2(const float* __restrict__ z0, const float* __restrict__ VinvT,
                        const float* __restrict__ Lw,
                        ushort_t* __restrict__ Wchk, ushort_t* __restrict__ Lws){
  __shared__ float zr[8][256];
  const int bid = blockIdx.x, tid = threadIdx.x;
  if (bid < 256){
    const int b0 = bid * 8;
    #pragma unroll
    for (int r = 0; r < 8; ++r) zr[r][tid] = z0[(size_t)(b0+r)*D_ + tid];
    __syncthreads();
    float acc[8] = {0.f,0.f,0.f,0.f,0.f,0.f,0.f,0.f};
    #pragma unroll 4
    for (int j = 0; j < D_; ++j){
      const float vj = VinvT[j*D_ + tid];
      #pragma unroll
      for (int r = 0; r < 8; ++r) acc[r] += zr[r][j] * vj;
    }
    #pragma unroll
    for (int r = 0; r < 8; ++r)
      Wchk[(size_t)(b0+r)*D_ + tid] = f2bf(acc[r]);
    return;
  }
  const int f = bid - 256;             // 0..31
  if (tid >= 64) return;
  const int l = tid, lm = l & 15, lh = l >> 4;
  const int it = f >> 1, kc2 = f & 1;
  const int ig = it*16 + lm;
  #pragma unroll
  for (int j = 0; j < 8; ++j){
    const int k = 32*kc2 + 4*lh + (j & 3) + 16*(j >> 2);
    Lws[(f*64 + l)*8 + j] = f2bf(k < UD_ ? Lw[ig*UD_ + k] : 0.f);
  }
}

// Pack augmented A fragments: rows 0..255 = V (Z), 256..335 = [Cw | dt*D] (Y). K=320.
__global__ void k_packA(const float* __restrict__ V, const float* __restrict__ Cw,
                        const float* __restrict__ Dmat, const float* __restrict__ dt,
                        ushort_t* __restrict__ Af){
  const int mt = blockIdx.x / 10, kc = blockIdx.x % 10;
  const int l = threadIdx.x, lm = l & 15, lh = l >> 4;
  const float dts = dt[0];
  #pragma unroll
  for (int j = 0; j < 8; ++j){
    const int k = 32*kc + 4*lh + (j & 3) + 16*(j >> 2);
    float val = 0.f;
    if (mt < 16){
      if (kc < 8) val = V[(mt*16 + lm)*D_ + k];
    } else {
      const int n = (mt - 16)*16 + lm;
      if (kc < 8) val = Cw[n*D_ + k];
      else { const int ku = k - 256; if (ku < UD_) val = dts * Dmat[n*UD_ + ku]; }
    }
    Af[((size_t)(mt*10 + kc)*64 + l)*8 + j] = f2bf(val);
  }
}

// ---------------- phase 1: boundary scan (barrier-free, 2-deep prefetch) ----------------
// 256 blocks = 128 bq x 2 ih; 256 thr = 4 waves; wave owns 2 eigen-it blocks,
// all 4 waves share the same 16 batch rows (per-lane u loads, L1-merged).
#define SCAN_STEP(UA, UB, UC, TT) do {                                          \
  union { ushort_t us[8]; bf16x8 v; } c0, c1;                                   \
  c0.us[0]=f2bf((UA).x); c0.us[1]=f2bf((UA).y); c0.us[2]=f2bf((UA).z); c0.us[3]=f2bf((UA).w); \
  c0.us[4]=f2bf((UB).x); c0.us[5]=f2bf((UB).y); c0.us[6]=f2bf((UB).z); c0.us[7]=f2bf((UB).w); \
  c1.us[0]=f2bf((UC).x); c1.us[1]=f2bf((UC).y); c1.us[2]=f2bf((UC).z); c1.us[3]=f2bf((UC).w); \
  c1.us[4]=0; c1.us[5]=0; c1.us[6]=0; c1.us[7]=0;                               \
  _Pragma("unroll")                                                             \
  for (int q = 0; q < 2; ++q){                                                  \
    f32x4 acc = {0.f,0.f,0.f,0.f};                                              \
    acc = mfma16(lwf[q*2+0], c0.v, acc);                                        \
    acc = mfma16(lwf[q*2+1], c1.v, acc);                                        \
    _Pragma("unroll")                                                           \
    for (int r = 0; r < 4; ++r) w[q*4+r] = lamr[q*4+r]*w[q*4+r] + acc[r];       \
  }                                                                             \
  if ((((TT) & 7) == 7) && ((TT) < T_-1)){                                      \
    const int c2 = ((TT)+1) >> 3;                                               \
    _Pragma("unroll")                                                           \
    for (int q = 0; q < 2; ++q){                                                \
      const int i = (itb+q)*16 + 4*lh;                                          \
      ushort4 o; o.x=f2bf(w[q*4+0]); o.y=f2bf(w[q*4+1]); o.z=f2bf(w[q*4+2]); o.w=f2bf(w[q*4+3]); \
      *(ushort4*)(Wchk + ((size_t)c2*B_ + row)*D_ + i) = o;                     \
    }                                                                           \
  }                                                                             \
} while(0)

__global__ void __launch_bounds__(256) k_scan(const float* __restrict__ U,
    const ushort_t* __restrict__ Lws, const float* __restrict__ lam,
    ushort_t* __restrict__ Wchk){
  const int tid = threadIdx.x;
  const int wid = tid >> 6, l = tid & 63;
  const int lm = l & 15, lh = l >> 4;
  const int bq = blockIdx.x >> 1, ih = blockIdx.x & 1;
  const int b0 = bq * 16;
  const int row = b0 + lm;
  const int itb = ih*8 + wid*2;

  bf16x8 lwf[4];
  #pragma unroll
  for (int q = 0; q < 2; ++q)
    #pragma unroll
    for (int c = 0; c < 2; ++c)
      lwf[q*2 + c] = *(const bf16x8*)(Lws + ((size_t)(((itb+q)*2 + c)*64 + l))*8);

  float lamr[8], w[8];
  #pragma unroll
  for (int q = 0; q < 2; ++q){
    const int i = (itb+q)*16 + 4*lh;
    const float4 lv = *(const float4*)&lam[i];
    const ushort4 wu = *(const ushort4*)(Wchk + (size_t)row*D_ + i);
    lamr[q*4+0]=lv.x; lamr[q*4+1]=lv.y; lamr[q*4+2]=lv.z; lamr[q*4+3]=lv.w;
    w[q*4+0]=bf2f(wu.x); w[q*4+1]=bf2f(wu.y); w[q*4+2]=bf2f(wu.z); w[q*4+3]=bf2f(wu.w);
  }

  const size_t TS = (size_t)B_ * UD_;
  const float* Urow = U + (size_t)row * UD_;
  float4 Aa, Ab, Ac, Ba, Bb, Bc;
  Aa = *(const float4*)&Urow[4*lh]; Ab = *(const float4*)&Urow[16+4*lh]; Ac = *(const float4*)&Urow[32+4*lh];
  { const float* Up = Urow + TS;
    Ba = *(const float4*)&Up[4*lh]; Bb = *(const float4*)&Up[16+4*lh]; Bc = *(const float4*)&Up[32+4*lh]; }

  #pragma unroll 1
  for (int tt = 0; tt < 64; ++tt){
    const int t0 = 2*tt;
    SCAN_STEP(Aa, Ab, Ac, t0);
    if (t0 + 2 < T_){
      const float* Up = Urow + (size_t)(t0+2)*TS;
      Aa = *(const float4*)&Up[4*lh]; Ab = *(const float4*)&Up[16+4*lh]; Ac = *(const float4*)&Up[32+4*lh];
    }
    SCAN_STEP(Ba, Bb, Bc, t0+1);
    if (t0 + 3 < T_){
      const float* Up = Urow + (size_t)(t0+3)*TS;
      Ba = *(const float4*)&Up[4*lh]; Bb = *(const float4*)&Up[16+4*lh]; Bc = *(const float4*)&Up[32+4*lh];
    }
  }
}

// ---------------- fused replay + output GEMM (barrier-free main loop) ----------------
// 256 blocks = 16 bq(128 rows) x 16 ch; 512 thr = 8 independent waves (16 rows each).
// LDS: Af Z-strips 0..14 (120K) + Lws (32K) + dVd (1K) + lam (1K) = 156672 B, staged once.
// Z strip 15 + all 5 Y strips read from global (L2-hot, 210 KB shared by all blocks).
__global__ void __launch_bounds__(512, 2) k_fused(
    const float* __restrict__ U, const ushort_t* __restrict__ Af,
    const ushort_t* __restrict__ Lws, const float* __restrict__ lam,
    const float* __restrict__ dVd, const ushort_t* __restrict__ Wchk,
    float* __restrict__ outZ, float* __restrict__ outY){
  __shared__ __align__(16) ushort_t AfL[15*8*512];   // 122880 B
  __shared__ __align__(16) ushort_t LwsL[32*512];    // 32768 B
  __shared__ __align__(16) float    dVdL[256];       // 1024 B
  __shared__ __align__(16) float    lamL[256];       // 1024 B

  const int tid = threadIdx.x;
  const int ch = blockIdx.x & 15;
  const int bq = blockIdx.x >> 4;
  const int wid = tid >> 6, l = tid & 63;
  const int lm = l & 15, lh = l >> 4;
  const int col = bq*128 + wid*16 + lm;

  // one-time staging
  {
    const uint4* gsrc = (const uint4*)Af;
    uint4* dst = (uint4*)AfL;
    #pragma unroll
    for (int r = 0; r < 15; ++r){
      const int i = r*512 + tid;
      const int fz = i >> 6, wq = i & 63;
      const int mt = fz >> 3, kc = fz & 7;
      dst[i] = gsrc[(mt*10 + kc)*64 + wq];
    }
    const uint4* ls = (const uint4*)Lws;
    uint4* ld = (uint4*)LwsL;
    #pragma unroll
    for (int r = 0; r < 4; ++r) ld[r*512 + tid] = ls[r*512 + tid];
    if (tid < 64) ((float4*)dVdL)[tid] = ((const float4*)dVd)[tid];
    else if (tid < 128) ((float4*)lamL)[tid-64] = ((const float4*)lam)[tid-64];
  }

  // boundary w (f32 state in regs; lam stays in LDS)
  float w[64];
  #pragma unroll
  for (int kc = 0; kc < 8; ++kc)
    #pragma unroll
    for (int h = 0; h < 2; ++h){
      const int i = 32*kc + 16*h + 4*lh;
      const ushort4 wu = *(const ushort4*)(Wchk + ((size_t)ch*B_ + col)*D_ + i);
      const int e = 8*kc + 4*h;
      w[e+0]=bf2f(wu.x); w[e+1]=bf2f(wu.y); w[e+2]=bf2f(wu.z); w[e+3]=bf2f(wu.w);
    }

  // u prefetch for first step
  const size_t TS = (size_t)B_ * UD_;
  const float* Ucol = U + (size_t)col * UD_;
  float4 ua, ub, uc;
  {
    const float* Ut = Ucol + (size_t)(ch*8)*TS;
    ua = *(const float4*)&Ut[4*lh]; ub = *(const float4*)&Ut[16+4*lh]; uc = *(const float4*)&Ut[32+4*lh];
  }

  __syncthreads();   // the only block-wide barrier

  #pragma unroll 1
  for (int s = 0; s < 8; ++s){
    const int t = ch*8 + s;
    // build u fragments
    bf16x8 uf0, uf1;
    {
      union { ushort_t us[8]; bf16x8 v; } cv;
      cv.us[0]=f2bf(ua.x); cv.us[1]=f2bf(ua.y); cv.us[2]=f2bf(ua.z); cv.us[3]=f2bf(ua.w);
      cv.us[4]=f2bf(ub.x); cv.us[5]=f2bf(ub.y); cv.us[6]=f2bf(ub.z); cv.us[7]=f2bf(ub.w);
      uf0 = cv.v;
      cv.us[0]=f2bf(uc.x); cv.us[1]=f2bf(uc.y); cv.us[2]=f2bf(uc.z); cv.us[3]=f2bf(uc.w);
      cv.us[4]=0; cv.us[5]=0; cv.us[6]=0; cv.us[7]=0;
      uf1 = cv.v;
    }
    if (s < 7){
      const float* Ut = Ucol + (size_t)(t+1)*TS;
      ua = *(const float4*)&Ut[4*lh]; ub = *(const float4*)&Ut[16+4*lh]; uc = *(const float4*)&Ut[32+4*lh];
    }
    // scan step (lam from LDS)
    #pragma unroll
    for (int it = 0; it < 16; ++it){
      const bf16x8 a0 = *(const bf16x8*)&LwsL[((it*2+0)*64 + l)*8];
      const bf16x8 a1 = *(const bf16x8*)&LwsL[((it*2+1)*64 + l)*8];
      const float4 lv = *(const float4*)&lamL[32*(it>>1) + 16*(it&1) + 4*lh];
      f32x4 acc = {0.f,0.f,0.f,0.f};
      acc = mfma16(a0, uf0, acc);
      acc = mfma16(a1, uf1, acc);
      const int e0 = 8*(it>>1) + 4*(it&1);
      w[e0+0] = lv.x*w[e0+0] + acc[0];
      w[e0+1] = lv.y*w[e0+1] + acc[1];
      w[e0+2] = lv.z*w[e0+2] + acc[2];
      w[e0+3] = lv.w*w[e0+3] + acc[3];
    }
    // pack w fragments
    bf16x8 wfr[8];
    #pragma unroll
    for (int kc = 0; kc < 8; ++kc){
      union { ushort_t us[8]; bf16x8 v; } cv;
      #pragma unroll
      for (int j = 0; j < 8; ++j) cv.us[j] = f2bf(w[8*kc + j]);
      wfr[kc] = cv.v;
    }
    // Z strips: direct stores (lanes lh=0..3 give contiguous 64 B per batch row)
    float* zrow = outZ + ((size_t)t*B_ + col)*D_;
    #pragma unroll
    for (int mt = 0; mt < 16; ++mt){
      f32x4 acc = {0.f,0.f,0.f,0.f};
      #pragma unroll
      for (int kc = 0; kc < 8; ++kc){
        bf16x8 af;
        if (mt < 15) af = *(const bf16x8*)&AfL[((mt*8+kc)*64 + l)*8];
        else         af = *(const bf16x8*)(Af + ((size_t)((150+kc)*64 + l))*8);
        acc = mfma16(af, wfr[kc], acc);
      }
      const float4 dv = *(const float4*)&dVdL[mt*16 + 4*lh];
      acc[0] += dv.x * (float)wfr[mt>>1][0 + 4*(mt&1)];
      acc[1] += dv.y * (float)wfr[mt>>1][1 + 4*(mt&1)];
      acc[2] += dv.z * (float)wfr[mt>>1][2 + 4*(mt&1)];
      acc[3] += dv.w * (float)wfr[mt>>1][3 + 4*(mt&1)];
      *(float4*)&zrow[mt*16 + 4*lh] = make_float4(acc[0],acc[1],acc[2],acc[3]);
    }
    // Y strips (A-frags from global, L2-hot)
    float* yrow = outY + ((size_t)t*B_ + col)*NO_;
    #pragma unroll 1
    for (int my = 0; my < 5; ++my){
      const ushort_t* Ay = Af + (size_t)((16+my)*10)*512;
      f32x4 acc = {0.f,0.f,0.f,0.f};
      #pragma unroll
      for (int kc = 0; kc < 8; ++kc){
        const bf16x8 af = *(const bf16x8*)(Ay + (kc*64 + l)*8);
        acc = mfma16(af, wfr[kc], acc);
      }
      {
        const bf16x8 af8 = *(const bf16x8*)(Ay + (8*64 + l)*8);
        const bf16x8 af9 = *(const bf16x8*)(Ay + (9*64 + l)*8);
        acc = mfma16(af8, uf0, acc);
        acc = mfma16(af9, uf1, acc);
      }
      *(float4*)&yrow[my*16 + 4*lh] = make_float4(acc[0],acc[1],acc[2],acc[3]);
    }
  }
}

// ---------------- launcher ----------------
extern "C" void kernel_launch(void* const* d_in, const int* in_sizes, int n_in,
                              void* d_out, int out_size, void* d_ws, size_t ws_size,
                              hipStream_t stream){
  const float* z0  = (const float*)d_in[0];
  const float* dt  = (const float*)d_in[2];
  const float* U   = (const float*)d_in[3];
  const float* eig = (const float*)d_in[4];
  const float* V   = (const float*)d_in[5];
  const float* L   = (const float*)d_in[6];
  const float* C   = (const float*)d_in[7];
  const float* Dm  = (const float*)d_in[8];
  float* outZ = (float*)d_out;
  float* outY = outZ + (size_t)T_*B_*D_;

  char* ws = (char*)d_ws;
  float* Xa    = (float*)(ws + 0);        // later reused as VinvT
  float* Xb    = (float*)(ws + 262144);
  float* Tt    = (float*)(ws + 524288);
  float* Lw    = (float*)(ws + 786432);
  float* Cw    = (float*)(ws + 835584);
  float* lam   = (float*)(ws + 917504);
  float* dVd   = (float*)(ws + 918528);
  ushort_t* Af   = (ushort_t*)(ws + 919552);
  ushort_t* Lws  = (ushort_t*)(ws + 1134592);
  ushort_t* Wchk = (ushort_t*)(ws + 1167360);
  if (ws_size < 17944576u) return;

  k_init<<<256,256,0,stream>>>(V, eig, Xa, lam);
  // Newton-Schulz, 3 iters from X0 = 2I - V  -> Vinv = Xb
  k_mm_mul<<<256,256,0,stream>>>(V, Xa, Tt);
  k_mm_upd<<<256,256,0,stream>>>(Xa, Tt, Xb);
  k_mm_mul<<<256,256,0,stream>>>(V, Xb, Tt);
  k_mm_upd<<<256,256,0,stream>>>(Xb, Tt, Xa);
  k_mm_mul<<<256,256,0,stream>>>(V, Xa, Tt);
  k_mm_upd<<<256,256,0,stream>>>(Xa, Tt, Xb);
  k_prep1<<<592,256,0,stream>>>(Xb, V, L, C, dt, /*VinvT=*/Xa, Lw, Cw, dVd);
  k_prep2<<<288,256,0,stream>>>(z0, /*VinvT=*/Xa, Lw, Wchk, Lws);
  k_packA<<<210,64,0,stream>>>(V, Cw, Dm, dt, Af);
  k_scan<<<256,256,0,stream>>>(U, Lws, lam, Wchk);
  k_fused<<<256,512,0,stream>>>(U, Af, Lws, lam, dVd, Wchk, outZ, outY);
}

// Round 2
// 1190.720 us; speedup vs baseline: 1.0000x; 1.0000x over previous
//
#include <hip/hip_runtime.h>

#define D_   256
#define UD_  48
#define NO_  80
#define T_   128
#define B_   2048

typedef __bf16 bf16x8 __attribute__((ext_vector_type(8)));
typedef float  f32x4  __attribute__((ext_vector_type(4)));
typedef unsigned short ushort_t;

static __device__ __forceinline__ ushort_t f2bf(float f){
  return __builtin_bit_cast(ushort_t, (__bf16)f);
}
static __device__ __forceinline__ float bf2f(ushort_t u){
  union { unsigned int i; float f; } c; c.i = ((unsigned int)u) << 16; return c.f;
}
static __device__ __forceinline__ f32x4 mfma16(bf16x8 a, bf16x8 b, f32x4 c){
  return __builtin_amdgcn_mfma_f32_16x16x32_bf16(a, b, c, 0, 0, 0);
}

// ---------------- prep ----------------

__global__ void k_init(const float* __restrict__ V, const float* __restrict__ eig,
                       float* __restrict__ Xa, float* __restrict__ lam){
  const int i = blockIdx.x, j = threadIdx.x;
  Xa[i*D_ + j] = (i == j ? 2.0f : 0.0f) - V[i*D_ + j];
  if (j == 0) lam[i] = 0.99f / (1.0f + expf(-eig[i]));
}

__global__ void k_mm_mul(const float* __restrict__ A, const float* __restrict__ B,
                         float* __restrict__ Cm){
  const int i = blockIdx.x, j = threadIdx.x;
  const float* Ar = A + i*D_;
  float a0=0.f,a1=0.f,a2=0.f,a3=0.f;
  #pragma unroll 4
  for (int k = 0; k < D_; k += 4){
    a0 += Ar[k+0] * B[(k+0)*D_ + j];
    a1 += Ar[k+1] * B[(k+1)*D_ + j];
    a2 += Ar[k+2] * B[(k+2)*D_ + j];
    a3 += Ar[k+3] * B[(k+3)*D_ + j];
  }
  Cm[i*D_ + j] = (a0+a1)+(a2+a3);
}

__global__ void k_mm_upd(const float* __restrict__ X, const float* __restrict__ Tm,
                         float* __restrict__ Xn){
  const int i = blockIdx.x, j = threadIdx.x;
  const float* Xr = X + i*D_;
  float a0=0.f,a1=0.f,a2=0.f,a3=0.f;
  #pragma unroll 4
  for (int k = 0; k < D_; k += 4){
    a0 += Xr[k+0] * Tm[(k+0)*D_ + j];
    a1 += Xr[k+1] * Tm[(k+1)*D_ + j];
    a2 += Xr[k+2] * Tm[(k+2)*D_ + j];
    a3 += Xr[k+3] * Tm[(k+3)*D_ + j];
  }
  Xn[i*D_ + j] = 2.0f*Xr[j] - ((a0+a1)+(a2+a3));
}

// VinvT = Vinv^T (+dVd); Lw = dt * Vinv @ L; Cw = C @ V
__global__ void k_prep1(const float* __restrict__ Vinv, const float* __restrict__ V,
                        const float* __restrict__ Lm, const float* __restrict__ Cmat,
                        const float* __restrict__ dt,
                        float* __restrict__ VinvT, float* __restrict__ Lw,
                        float* __restrict__ Cw, float* __restrict__ dVd){
  const int bid = blockIdx.x, tid = threadIdx.x;
  if (bid < 256){
    VinvT[tid*D_ + bid] = Vinv[bid*D_ + tid];
    if (tid == bid){ float v = V[bid*D_ + bid]; dVd[bid] = v - bf2f(f2bf(v)); }
  } else if (bid < 512){
    const int i = bid - 256;
    if (tid < UD_){
      float acc = 0.f;
      #pragma unroll 4
      for (int j = 0; j < D_; ++j) acc += Vinv[i*D_ + j] * Lm[j*UD_ + tid];
      Lw[i*UD_ + tid] = acc * dt[0];
    }
  } else {
    const int n = bid - 512;
    float acc = 0.f;
    #pragma unroll 4
    for (int j = 0; j < D_; ++j) acc += Cmat[n*D_ + j] * V[j*D_ + tid];
    Cw[n*D_ + tid] = acc;
  }
}

// w0 = z0 @ VinvT -> Wchk[0] (bf16), 8 rows/block; pack Lws A-fragments.
// k-map (bijective, A/B consistent): k = 32*kc + 4*lh + (j&3) + 16*(j>>2)
__global__ void k_prep2(const float* __restrict__ z0, const float* __restrict__ VinvT,
                        const float* __restrict__ Lw,
                        ushort_t* __restrict__ Wchk, ushort_t* __restrict__ Lws){
  __shared__ float zr[8][256];
  const int bid = blockIdx.x, tid = threadIdx.x;
  if (bid < 256){
    const int b0 = bid * 8;
    #pragma unroll
    for (int r = 0; r < 8; ++r) zr[r][tid] = z0[(size_t)(b0+r)*D_ + tid];
    __syncthreads();
    float acc[8] = {0.f,0.f,0.f,0.f,0.f,0.f,0.f,0.f};
    #pragma unroll 4
    for (int j = 0; j < D_; ++j){
      const float vj = VinvT[j*D_ + tid];
      #pragma unroll
      for (int r = 0; r < 8; ++r) acc[r] += zr[r][j] * vj;
    }
    #pragma unroll
    for (int r = 0; r < 8; ++r)
      Wchk[(size_t)(b0+r)*D_ + tid] = f2bf(acc[r]);
    return;
  }
  const int f = bid - 256;             // 0..31
  if (tid >= 64) return;
  const int l = tid, lm = l & 15, lh = l >> 4;
  const int it = f >> 1, kc2 = f & 1;
  const int ig = it*16 + lm;
  #pragma unroll
  for (int j = 0; j < 8; ++j){
    const int k = 32*kc2 + 4*lh + (j & 3) + 16*(j >> 2);
    Lws[(f*64 + l)*8 + j] = f2bf(k < UD_ ? Lw[ig*UD_ + k] : 0.f);
  }
}

// Pack augmented A fragments: rows 0..255 = V (Z), 256..335 = [Cw | dt*D] (Y). K=320.
__global__ void k_packA(const float* __restrict__ V, const float* __restrict__ Cw,
                        const float* __restrict__ Dmat, const float* __restrict__ dt,
                        ushort_t* __restrict__ Af){
  const int mt = blockIdx.x / 10, kc = blockIdx.x % 10;
  const int l = threadIdx.x, lm = l & 15, lh = l >> 4;
  const float dts = dt[0];
  #pragma unroll
  for (int j = 0; j < 8; ++j){
    const int k = 32*kc + 4*lh + (j & 3) + 16*(j >> 2);
    float val = 0.f;
    if (mt < 16){
      if (kc < 8) val = V[(mt*16 + lm)*D_ + k];
    } else {
      const int n = (mt - 16)*16 + lm;
      if (kc < 8) val = Cw[n*D_ + k];
      else { const int ku = k - 256; if (ku < UD_) val = dts * Dmat[n*UD_ + ku]; }
    }
    Af[((size_t)(mt*10 + kc)*64 + l)*8 + j] = f2bf(val);
  }
}

// ---------------- phase 1: boundary scan (barrier-free, 2-deep prefetch) ----------------
// 256 blocks = 128 bq x 2 ih; 256 thr = 4 waves; wave owns 2 eigen-it blocks,
// all 4 waves share the same 16 batch rows (per-lane u loads, L1-merged).
#define SCAN_STEP(UA, UB, UC, TT) do {                                          \
  union { ushort_t us[8]; bf16x8 v; } c0, c1;                                   \
  c0.us[0]=f2bf((UA).x); c0.us[1]=f2bf((UA).y); c0.us[2]=f2bf((UA).z); c0.us[3]=f2bf((UA).w); \
  c0.us[4]=f2bf((UB).x); c0.us[5]=f2bf((UB).y); c0.us[6]=f2bf((UB).z); c0.us[7]=f2bf((UB).w); \
  c1.us[0]=f2bf((UC).x); c1.us[1]=f2bf((UC).y); c1.us[2]=f2bf((UC).z); c1.us[3]=f2bf((UC).w); \
  c1.us[4]=0; c1.us[5]=0; c1.us[6]=0; c1.us[7]=0;                               \
  _Pragma("unroll")                                                             \
  for (int q = 0; q < 2; ++q){                                                  \
    f32x4 acc = {0.f,0.f,0.f,0.f};                                              \
    acc = mfma16(lwf[q*2+0], c0.v, acc);                                        \
    acc = mfma16(lwf[q*2+1], c1.v, acc);                                        \
    _Pragma("unroll")                                                           \
    for (int r = 0; r < 4; ++r) w[q*4+r] = lamr[q*4+r]*w[q*4+r] + acc[r];       \
  }                                                                             \
  if ((((TT) & 7) == 7) && ((TT) < T_-1)){                                      \
    const int c2 = ((TT)+1) >> 3;                                               \
    _Pragma("unroll")                                                           \
    for (int q = 0; q < 2; ++q){                                                \
      const int i = (itb+q)*16 + 4*lh;                                          \
      ushort4 o; o.x=f2bf(w[q*4+0]); o.y=f2bf(w[q*4+1]); o.z=f2bf(w[q*4+2]); o.w=f2bf(w[q*4+3]); \
      *(ushort4*)(Wchk + ((size_t)c2*B_ + row)*D_ + i) = o;                     \
    }                                                                           \
  }                                                                             \
} while(0)

__global__ void __launch_bounds__(256) k_scan(const float* __restrict__ U,
    const ushort_t* __restrict__ Lws, const float* __restrict__ lam,
    ushort_t* __restrict__ Wchk){
  const int tid = threadIdx.x;
  const int wid = tid >> 6, l = tid & 63;
  const int lm = l & 15, lh = l >> 4;
  const int bq = blockIdx.x >> 1, ih = blockIdx.x & 1;
  const int b0 = bq * 16;
  const int row = b0 + lm;
  const int itb = ih*8 + wid*2;

  bf16x8 lwf[4];
  #pragma unroll
  for (int q = 0; q < 2; ++q)
    #pragma unroll
    for (int c = 0; c < 2; ++c)
      lwf[q*2 + c] = *(const bf16x8*)(Lws + ((size_t)(((itb+q)*2 + c)*64 + l))*8);

  float lamr[8], w[8];
  #pragma unroll
  for (int q = 0; q < 2; ++q){
    const int i = (itb+q)*16 + 4*lh;
    const float4 lv = *(const float4*)&lam[i];
    const ushort4 wu = *(const ushort4*)(Wchk + (size_t)row*D_ + i);
    lamr[q*4+0]=lv.x; lamr[q*4+1]=lv.y; lamr[q*4+2]=lv.z; lamr[q*4+3]=lv.w;
    w[q*4+0]=bf2f(wu.x); w[q*4+1]=bf2f(wu.y); w[q*4+2]=bf2f(wu.z); w[q*4+3]=bf2f(wu.w);
  }

  const size_t TS = (size_t)B_ * UD_;
  const float* Urow = U + (size_t)row * UD_;
  float4 Aa, Ab, Ac, Ba, Bb, Bc;
  Aa = *(const float4*)&Urow[4*lh]; Ab = *(const float4*)&Urow[16+4*lh]; Ac = *(const float4*)&Urow[32+4*lh];
  { const float* Up = Urow + TS;
    Ba = *(const float4*)&Up[4*lh]; Bb = *(const float4*)&Up[16+4*lh]; Bc = *(const float4*)&Up[32+4*lh]; }

  #pragma unroll 1
  for (int tt = 0; tt < 64; ++tt){
    const int t0 = 2*tt;
    SCAN_STEP(Aa, Ab, Ac, t0);
    if (t0 + 2 < T_){
      const float* Up = Urow + (size_t)(t0+2)*TS;
      Aa = *(const float4*)&Up[4*lh]; Ab = *(const float4*)&Up[16+4*lh]; Ac = *(const float4*)&Up[32+4*lh];
    }
    SCAN_STEP(Ba, Bb, Bc, t0+1);
    if (t0 + 3 < T_){
      const float* Up = Urow + (size_t)(t0+3)*TS;
      Ba = *(const float4*)&Up[4*lh]; Bb = *(const float4*)&Up[16+4*lh]; Bc = *(const float4*)&Up[32+4*lh];
    }
  }
}

// ---------------- fused replay + output GEMM (barrier-free main loop) ----------------
// 256 blocks = 16 bq(128 rows) x 16 ch; 512 thr = 8 independent waves (16 rows each).
// LDS: Af Z-strips 0..14 (120K) + Lws (32K) + dVd (1K) + lam (1K) = 156672 B, staged once.
// LDS caps residency at 1 block/CU, so launch_bounds min-waves = 1 (2 waves/SIMD
// from the 512-thr block itself) -> 256 VGPR budget, no spill of w[64]+wfr[8].
__global__ void __launch_bounds__(512, 1) k_fused(
    const float* __restrict__ U, const ushort_t* __restrict__ Af,
    const ushort_t* __restrict__ Lws, const float* __restrict__ lam,
    const float* __restrict__ dVd, const ushort_t* __restrict__ Wchk,
    float* __restrict__ outZ, float* __restrict__ outY){
  __shared__ __align__(16) ushort_t AfL[15*8*512];   // 122880 B
  __shared__ __align__(16) ushort_t LwsL[32*512];    // 32768 B
  __shared__ __align__(16) float    dVdL[256];       // 1024 B
  __shared__ __align__(16) float    lamL[256];       // 1024 B

  const int tid = threadIdx.x;
  const int ch = blockIdx.x & 15;
  const int bq = blockIdx.x >> 4;
  const int wid = tid >> 6, l = tid & 63;
  const int lm = l & 15, lh = l >> 4;
  const int col = bq*128 + wid*16 + lm;

  // one-time staging
  {
    const uint4* gsrc = (const uint4*)Af;
    uint4* dst = (uint4*)AfL;
    #pragma unroll
    for (int r = 0; r < 15; ++r){
      const int i = r*512 + tid;
      const int fz = i >> 6, wq = i & 63;
      const int mt = fz >> 3, kc = fz & 7;
      dst[i] = gsrc[(mt*10 + kc)*64 + wq];
    }
    const uint4* ls = (const uint4*)Lws;
    uint4* ld = (uint4*)LwsL;
    #pragma unroll
    for (int r = 0; r < 4; ++r) ld[r*512 + tid] = ls[r*512 + tid];
    if (tid < 64) ((float4*)dVdL)[tid] = ((const float4*)dVd)[tid];
    else if (tid < 128) ((float4*)lamL)[tid-64] = ((const float4*)lam)[tid-64];
  }

  // boundary w (f32 state in regs; lam stays in LDS)
  float w[64];
  #pragma unroll
  for (int kc = 0; kc < 8; ++kc)
    #pragma unroll
    for (int h = 0; h < 2; ++h){
      const int i = 32*kc + 16*h + 4*lh;
      const ushort4 wu = *(const ushort4*)(Wchk + ((size_t)ch*B_ + col)*D_ + i);
      const int e = 8*kc + 4*h;
      w[e+0]=bf2f(wu.x); w[e+1]=bf2f(wu.y); w[e+2]=bf2f(wu.z); w[e+3]=bf2f(wu.w);
    }

  // u prefetch for first step
  const size_t TS = (size_t)B_ * UD_;
  const float* Ucol = U + (size_t)col * UD_;
  float4 ua, ub, uc;
  {
    const float* Ut = Ucol + (size_t)(ch*8)*TS;
    ua = *(const float4*)&Ut[4*lh]; ub = *(const float4*)&Ut[16+4*lh]; uc = *(const float4*)&Ut[32+4*lh];
  }

  __syncthreads();   // the only block-wide barrier

  #pragma unroll 1
  for (int s = 0; s < 8; ++s){
    const int t = ch*8 + s;
    // build u fragments
    bf16x8 uf0, uf1;
    {
      union { ushort_t us[8]; bf16x8 v; } cv;
      cv.us[0]=f2bf(ua.x); cv.us[1]=f2bf(ua.y); cv.us[2]=f2bf(ua.z); cv.us[3]=f2bf(ua.w);
      cv.us[4]=f2bf(ub.x); cv.us[5]=f2bf(ub.y); cv.us[6]=f2bf(ub.z); cv.us[7]=f2bf(ub.w);
      uf0 = cv.v;
      cv.us[0]=f2bf(uc.x); cv.us[1]=f2bf(uc.y); cv.us[2]=f2bf(uc.z); cv.us[3]=f2bf(uc.w);
      cv.us[4]=0; cv.us[5]=0; cv.us[6]=0; cv.us[7]=0;
      uf1 = cv.v;
    }
    if (s < 7){
      const float* Ut = Ucol + (size_t)(t+1)*TS;
      ua = *(const float4*)&Ut[4*lh]; ub = *(const float4*)&Ut[16+4*lh]; uc = *(const float4*)&Ut[32+4*lh];
    }
    // scan step (lam from LDS)
    #pragma unroll
    for (int it = 0; it < 16; ++it){
      const bf16x8 a0 = *(const bf16x8*)&LwsL[((it*2+0)*64 + l)*8];
      const bf16x8 a1 = *(const bf16x8*)&LwsL[((it*2+1)*64 + l)*8];
      const float4 lv = *(const float4*)&lamL[32*(it>>1) + 16*(it&1) + 4*lh];
      f32x4 acc = {0.f,0.f,0.f,0.f};
      acc = mfma16(a0, uf0, acc);
      acc = mfma16(a1, uf1, acc);
      const int e0 = 8*(it>>1) + 4*(it&1);
      w[e0+0] = lv.x*w[e0+0] + acc[0];
      w[e0+1] = lv.y*w[e0+1] + acc[1];
      w[e0+2] = lv.z*w[e0+2] + acc[2];
      w[e0+3] = lv.w*w[e0+3] + acc[3];
    }
    // pack w fragments
    bf16x8 wfr[8];
    #pragma unroll
    for (int kc = 0; kc < 8; ++kc){
      union { ushort_t us[8]; bf16x8 v; } cv;
      #pragma unroll
      for (int j = 0; j < 8; ++j) cv.us[j] = f2bf(w[8*kc + j]);
      wfr[kc] = cv.v;
    }
    // Z strips: direct stores (lanes lh=0..3 give contiguous 64 B per batch row)
    float* zrow = outZ + ((size_t)t*B_ + col)*D_;
    #pragma unroll
    for (int mt = 0; mt < 16; ++mt){
      f32x4 acc = {0.f,0.f,0.f,0.f};
      #pragma unroll
      for (int kc = 0; kc < 8; ++kc){
        bf16x8 af;
        if (mt < 15) af = *(const bf16x8*)&AfL[((mt*8+kc)*64 + l)*8];
        else         af = *(const bf16x8*)(Af + ((size_t)((150+kc)*64 + l))*8);
        acc = mfma16(af, wfr[kc], acc);
      }
      const float4 dv = *(const float4*)&dVdL[mt*16 + 4*lh];
      acc[0] += dv.x * (float)wfr[mt>>1][0 + 4*(mt&1)];
      acc[1] += dv.y * (float)wfr[mt>>1][1 + 4*(mt&1)];
      acc[2] += dv.z * (float)wfr[mt>>1][2 + 4*(mt&1)];
      acc[3] += dv.w * (float)wfr[mt>>1][3 + 4*(mt&1)];
      *(float4*)&zrow[mt*16 + 4*lh] = make_float4(acc[0],acc[1],acc[2],acc[3]);
    }
    // Y strips (A-frags from global, L2-hot)
    float* yrow = outY + ((size_t)t*B_ + col)*NO_;
    #pragma unroll 1
    for (int my = 0; my < 5; ++my){
      const ushort_t* Ay = Af + (size_t)((16+my)*10)*512;
      f32x4 acc = {0.f,0.f,0.f,0.f};
      #pragma unroll
      for (int kc = 0; kc < 8; ++kc){
        const bf16x8 af = *(const bf16x8*)(Ay + (kc*64 + l)*8);
        acc = mfma16(af, wfr[kc], acc);
      }
      {
        const bf16x8 af8 = *(const bf16x8*)(Ay + (8*64 + l)*8);
        const bf16x8 af9 = *(const bf16x8*)(Ay + (9*64 + l)*8);
        acc = mfma16(af8, uf0, acc);
        acc = mfma16(af9, uf1, acc);
      }
      *(float4*)&yrow[my*16 + 4*lh] = make_float4(acc[0],acc[1],acc[2],acc[3]);
    }
  }
}

// ---------------- launcher ----------------
extern "C" void kernel_launch(void* const* d_in, const int* in_sizes, int n_in,
                              void* d_out, int out_size, void* d_ws, size_t ws_size,
                              hipStream_t stream){
  const float* z0  = (const float*)d_in[0];
  const float* dt  = (const float*)d_in[2];
  const float* U   = (const float*)d_in[3];
  const float* eig = (const float*)d_in[4];
  const float* V   = (const float*)d_in[5];
  const float* L   = (const float*)d_in[6];
  const float* C   = (const float*)d_in[7];
  const float* Dm  = (const float*)d_in[8];
  float* outZ = (float*)d_out;
  float* outY = outZ + (size_t)T_*B_*D_;

  char* ws = (char*)d_ws;
  float* Xa    = (float*)(ws + 0);        // later reused as VinvT
  float* Xb    = (float*)(ws + 262144);
  float* Tt    = (float*)(ws + 524288);
  float* Lw    = (float*)(ws + 786432);
  float* Cw    = (float*)(ws + 835584);
  float* lam   = (float*)(ws + 917504);
  float* dVd   = (float*)(ws + 918528);
  ushort_t* Af   = (ushort_t*)(ws + 919552);
  ushort_t* Lws  = (ushort_t*)(ws + 1134592);
  ushort_t* Wchk = (ushort_t*)(ws + 1167360);
  if (ws_size < 17944576u) return;

  k_init<<<256,256,0,stream>>>(V, eig, Xa, lam);
  // Newton-Schulz, 3 iters from X0 = 2I - V  -> Vinv = Xb
  k_mm_mul<<<256,256,0,stream>>>(V, Xa, Tt);
  k_mm_upd<<<256,256,0,stream>>>(Xa, Tt, Xb);
  k_mm_mul<<<256,256,0,stream>>>(V, Xb, Tt);
  k_mm_upd<<<256,256,0,stream>>>(Xb, Tt, Xa);
  k_mm_mul<<<256,256,0,stream>>>(V, Xa, Tt);
  k_mm_upd<<<256,256,0,stream>>>(Xa, Tt, Xb);
  k_prep1<<<592,256,0,stream>>>(Xb, V, L, C, dt, /*VinvT=*/Xa, Lw, Cw, dVd);
  k_prep2<<<288,256,0,stream>>>(z0, /*VinvT=*/Xa, Lw, Wchk, Lws);
  k_packA<<<210,64,0,stream>>>(V, Cw, Dm, dt, Af);
  k_scan<<<256,256,0,stream>>>(U, Lws, lam, Wchk);
  k_fused<<<256,512,0,stream>>>(U, Af, Lws, lam, dVd, Wchk, outZ, outY);
}

// Round 3
// 932.929 us; speedup vs baseline: 1.2763x; 1.2763x over previous
//
#include <hip/hip_runtime.h>

#define D_   256
#define UD_  48
#define NO_  80
#define T_   128
#define B_   2048

typedef __bf16 bf16x8 __attribute__((ext_vector_type(8)));
typedef float  f32x4  __attribute__((ext_vector_type(4)));
typedef unsigned short ushort_t;

static __device__ __forceinline__ ushort_t f2bf(float f){
  return __builtin_bit_cast(ushort_t, (__bf16)f);
}
static __device__ __forceinline__ float bf2f(ushort_t u){
  union { unsigned int i; float f; } c; c.i = ((unsigned int)u) << 16; return c.f;
}
static __device__ __forceinline__ f32x4 mfma16(bf16x8 a, bf16x8 b, f32x4 c){
  return __builtin_amdgcn_mfma_f32_16x16x32_bf16(a, b, c, 0, 0, 0);
}

// ---------------- prep ----------------

__global__ void k_init(const float* __restrict__ V, const float* __restrict__ eig,
                       float* __restrict__ Xa, float* __restrict__ lam){
  const int i = blockIdx.x, j = threadIdx.x;
  Xa[i*D_ + j] = (i == j ? 2.0f : 0.0f) - V[i*D_ + j];
  if (j == 0) lam[i] = 0.99f / (1.0f + expf(-eig[i]));
}

__global__ void k_mm_mul(const float* __restrict__ A, const float* __restrict__ B,
                         float* __restrict__ Cm){
  const int i = blockIdx.x, j = threadIdx.x;
  const float* Ar = A + i*D_;
  float a0=0.f,a1=0.f,a2=0.f,a3=0.f;
  #pragma unroll 4
  for (int k = 0; k < D_; k += 4){
    a0 += Ar[k+0] * B[(k+0)*D_ + j];
    a1 += Ar[k+1] * B[(k+1)*D_ + j];
    a2 += Ar[k+2] * B[(k+2)*D_ + j];
    a3 += Ar[k+3] * B[(k+3)*D_ + j];
  }
  Cm[i*D_ + j] = (a0+a1)+(a2+a3);
}

__global__ void k_mm_upd(const float* __restrict__ X, const float* __restrict__ Tm,
                         float* __restrict__ Xn){
  const int i = blockIdx.x, j = threadIdx.x;
  const float* Xr = X + i*D_;
  float a0=0.f,a1=0.f,a2=0.f,a3=0.f;
  #pragma unroll 4
  for (int k = 0; k < D_; k += 4){
    a0 += Xr[k+0] * Tm[(k+0)*D_ + j];
    a1 += Xr[k+1] * Tm[(k+1)*D_ + j];
    a2 += Xr[k+2] * Tm[(k+2)*D_ + j];
    a3 += Xr[k+3] * Tm[(k+3)*D_ + j];
  }
  Xn[i*D_ + j] = 2.0f*Xr[j] - ((a0+a1)+(a2+a3));
}

// VinvT = Vinv^T (+dVd); Lw = dt * Vinv @ L; Cw = C @ V
__global__ void k_prep1(const float* __restrict__ Vinv, const float* __restrict__ V,
                        const float* __restrict__ Lm, const float* __restrict__ Cmat,
                        const float* __restrict__ dt,
                        float* __restrict__ VinvT, float* __restrict__ Lw,
                        float* __restrict__ Cw, float* __restrict__ dVd){
  const int bid = blockIdx.x, tid = threadIdx.x;
  if (bid < 256){
    VinvT[tid*D_ + bid] = Vinv[bid*D_ + tid];
    if (tid == bid){ float v = V[bid*D_ + bid]; dVd[bid] = v - bf2f(f2bf(v)); }
  } else if (bid < 512){
    const int i = bid - 256;
    if (tid < UD_){
      float acc = 0.f;
      #pragma unroll 4
      for (int j = 0; j < D_; ++j) acc += Vinv[i*D_ + j] * Lm[j*UD_ + tid];
      Lw[i*UD_ + tid] = acc * dt[0];
    }
  } else {
    const int n = bid - 512;
    float acc = 0.f;
    #pragma unroll 4
    for (int j = 0; j < D_; ++j) acc += Cmat[n*D_ + j] * V[j*D_ + tid];
    Cw[n*D_ + tid] = acc;
  }
}

// w0 = z0 @ VinvT -> Wchk[0] (bf16), 8 rows/block; pack Lws A-fragments.
// k-map (bijective, A/B consistent): k = 32*kc + 4*lh + (j&3) + 16*(j>>2)
__global__ void k_prep2(const float* __restrict__ z0, const float* __restrict__ VinvT,
                        const float* __restrict__ Lw,
                        ushort_t* __restrict__ Wchk, ushort_t* __restrict__ Lws){
  __shared__ float zr[8][256];
  const int bid = blockIdx.x, tid = threadIdx.x;
  if (bid < 256){
    const int b0 = bid * 8;
    #pragma unroll
    for (int r = 0; r < 8; ++r) zr[r][tid] = z0[(size_t)(b0+r)*D_ + tid];
    __syncthreads();
    float acc[8] = {0.f,0.f,0.f,0.f,0.f,0.f,0.f,0.f};
    #pragma unroll 4
    for (int j = 0; j < D_; ++j){
      const float vj = VinvT[j*D_ + tid];
      #pragma unroll
      for (int r = 0; r < 8; ++r) acc[r] += zr[r][j] * vj;
    }
    #pragma unroll
    for (int r = 0; r < 8; ++r)
      Wchk[(size_t)(b0+r)*D_ + tid] = f2bf(acc[r]);
    return;
  }
  const int f = bid - 256;             // 0..31
  if (tid >= 64) return;
  const int l = tid, lm = l & 15, lh = l >> 4;
  const int it = f >> 1, kc2 = f & 1;
  const int ig = it*16 + lm;
  #pragma unroll
  for (int j = 0; j < 8; ++j){
    const int k = 32*kc2 + 4*lh + (j & 3) + 16*(j >> 2);
    Lws[(f*64 + l)*8 + j] = f2bf(k < UD_ ? Lw[ig*UD_ + k] : 0.f);
  }
}

// Pack augmented A fragments: rows 0..255 = V (Z), 256..335 = [Cw | dt*D] (Y). K=320.
__global__ void k_packA(const float* __restrict__ V, const float* __restrict__ Cw,
                        const float* __restrict__ Dmat, const float* __restrict__ dt,
                        ushort_t* __restrict__ Af){
  const int mt = blockIdx.x / 10, kc = blockIdx.x % 10;
  const int l = threadIdx.x, lm = l & 15, lh = l >> 4;
  const float dts = dt[0];
  #pragma unroll
  for (int j = 0; j < 8; ++j){
    const int k = 32*kc + 4*lh + (j & 3) + 16*(j >> 2);
    float val = 0.f;
    if (mt < 16){
      if (kc < 8) val = V[(mt*16 + lm)*D_ + k];
    } else {
      const int n = (mt - 16)*16 + lm;
      if (kc < 8) val = Cw[n*D_ + k];
      else { const int ku = k - 256; if (ku < UD_) val = dts * Dmat[n*UD_ + ku]; }
    }
    Af[((size_t)(mt*10 + kc)*64 + l)*8 + j] = f2bf(val);
  }
}

// ---------------- phase 1: boundary scan (barrier-free, 2-deep prefetch) ----------------
// 256 blocks = 128 bq x 2 ih; 256 thr = 4 waves; wave owns 2 eigen-it blocks,
// all 4 waves share the same 16 batch rows (per-lane u loads, L1-merged).
#define SCAN_STEP(UA, UB, UC, TT) do {                                          \
  union { ushort_t us[8]; bf16x8 v; } c0, c1;                                   \
  c0.us[0]=f2bf((UA).x); c0.us[1]=f2bf((UA).y); c0.us[2]=f2bf((UA).z); c0.us[3]=f2bf((UA).w); \
  c0.us[4]=f2bf((UB).x); c0.us[5]=f2bf((UB).y); c0.us[6]=f2bf((UB).z); c0.us[7]=f2bf((UB).w); \
  c1.us[0]=f2bf((UC).x); c1.us[1]=f2bf((UC).y); c1.us[2]=f2bf((UC).z); c1.us[3]=f2bf((UC).w); \
  c1.us[4]=0; c1.us[5]=0; c1.us[6]=0; c1.us[7]=0;                               \
  _Pragma("unroll")                                                             \
  for (int q = 0; q < 2; ++q){                                                  \
    f32x4 acc = {0.f,0.f,0.f,0.f};                                              \
    acc = mfma16(lwf[q*2+0], c0.v, acc);                                        \
    acc = mfma16(lwf[q*2+1], c1.v, acc);                                        \
    _Pragma("unroll")                                                           \
    for (int r = 0; r < 4; ++r) w[q*4+r] = lamr[q*4+r]*w[q*4+r] + acc[r];       \
  }                                                                             \
  if ((((TT) & 7) == 7) && ((TT) < T_-1)){                                      \
    const int c2 = ((TT)+1) >> 3;                                               \
    _Pragma("unroll")                                                           \
    for (int q = 0; q < 2; ++q){                                                \
      const int i = (itb+q)*16 + 4*lh;                                          \
      ushort4 o; o.x=f2bf(w[q*4+0]); o.y=f2bf(w[q*4+1]); o.z=f2bf(w[q*4+2]); o.w=f2bf(w[q*4+3]); \
      *(ushort4*)(Wchk + ((size_t)c2*B_ + row)*D_ + i) = o;                     \
    }                                                                           \
  }                                                                             \
} while(0)

__global__ void __launch_bounds__(256) k_scan(const float* __restrict__ U,
    const ushort_t* __restrict__ Lws, const float* __restrict__ lam,
    ushort_t* __restrict__ Wchk){
  const int tid = threadIdx.x;
  const int wid = tid >> 6, l = tid & 63;
  const int lm = l & 15, lh = l >> 4;
  const int bq = blockIdx.x >> 1, ih = blockIdx.x & 1;
  const int b0 = bq * 16;
  const int row = b0 + lm;
  const int itb = ih*8 + wid*2;

  bf16x8 lwf[4];
  #pragma unroll
  for (int q = 0; q < 2; ++q)
    #pragma unroll
    for (int c = 0; c < 2; ++c)
      lwf[q*2 + c] = *(const bf16x8*)(Lws + ((size_t)(((itb+q)*2 + c)*64 + l))*8);

  float lamr[8], w[8];
  #pragma unroll
  for (int q = 0; q < 2; ++q){
    const int i = (itb+q)*16 + 4*lh;
    const float4 lv = *(const float4*)&lam[i];
    const ushort4 wu = *(const ushort4*)(Wchk + (size_t)row*D_ + i);
    lamr[q*4+0]=lv.x; lamr[q*4+1]=lv.y; lamr[q*4+2]=lv.z; lamr[q*4+3]=lv.w;
    w[q*4+0]=bf2f(wu.x); w[q*4+1]=bf2f(wu.y); w[q*4+2]=bf2f(wu.z); w[q*4+3]=bf2f(wu.w);
  }

  const size_t TS = (size_t)B_ * UD_;
  const float* Urow = U + (size_t)row * UD_;
  float4 Aa, Ab, Ac, Ba, Bb, Bc;
  Aa = *(const float4*)&Urow[4*lh]; Ab = *(const float4*)&Urow[16+4*lh]; Ac = *(const float4*)&Urow[32+4*lh];
  { const float* Up = Urow + TS;
    Ba = *(const float4*)&Up[4*lh]; Bb = *(const float4*)&Up[16+4*lh]; Bc = *(const float4*)&Up[32+4*lh]; }

  #pragma unroll 1
  for (int tt = 0; tt < 64; ++tt){
    const int t0 = 2*tt;
    SCAN_STEP(Aa, Ab, Ac, t0);
    if (t0 + 2 < T_){
      const float* Up = Urow + (size_t)(t0+2)*TS;
      Aa = *(const float4*)&Up[4*lh]; Ab = *(const float4*)&Up[16+4*lh]; Ac = *(const float4*)&Up[32+4*lh];
    }
    SCAN_STEP(Ba, Bb, Bc, t0+1);
    if (t0 + 3 < T_){
      const float* Up = Urow + (size_t)(t0+3)*TS;
      Ba = *(const float4*)&Up[4*lh]; Bb = *(const float4*)&Up[16+4*lh]; Bc = *(const float4*)&Up[32+4*lh];
    }
  }
}

// ---------------- fused replay + output GEMM (barrier-free main loop) ----------------
// 512 blocks = 32 bq(64 rows) x 16 ch; 256 thr = 4 waves; wave owns 16 rows,
// fully independent after the single staging barrier.
// 256-thr geometry is the one the allocator gives 256 VGPRs to (round-0 evidence);
// 512-thr blocks capped at 128 VGPR and spilled w[64]+wfr[8] (rounds 1-2, 1.4 GB scratch).
// LDS: Af Z-strips 0..14 (120K) + Lws (32K) + dVd (1K) + lam (1K) = 156672 B -> 1 block/CU.
__global__ void __launch_bounds__(256) k_fused(
    const float* __restrict__ U, const ushort_t* __restrict__ Af,
    const ushort_t* __restrict__ Lws, const float* __restrict__ lam,
    const float* __restrict__ dVd, const ushort_t* __restrict__ Wchk,
    float* __restrict__ outZ, float* __restrict__ outY){
  __shared__ __align__(16) ushort_t AfL[15*8*512];   // 122880 B
  __shared__ __align__(16) ushort_t LwsL[32*512];    // 32768 B
  __shared__ __align__(16) float    dVdL[256];       // 1024 B
  __shared__ __align__(16) float    lamL[256];       // 1024 B

  const int tid = threadIdx.x;
  const int ch = blockIdx.x & 15;
  const int bq = blockIdx.x >> 4;
  const int wid = tid >> 6, l = tid & 63;
  const int lm = l & 15, lh = l >> 4;
  const int col = bq*64 + wid*16 + lm;

  // one-time staging (256 threads)
  {
    const uint4* gsrc = (const uint4*)Af;
    uint4* dst = (uint4*)AfL;
    #pragma unroll
    for (int r = 0; r < 30; ++r){
      const int i = r*256 + tid;
      const int fz = i >> 6, wq = i & 63;
      const int mt = fz >> 3, kc = fz & 7;
      dst[i] = gsrc[(mt*10 + kc)*64 + wq];
    }
    const uint4* ls = (const uint4*)Lws;
    uint4* ld = (uint4*)LwsL;
    #pragma unroll
    for (int r = 0; r < 8; ++r) ld[r*256 + tid] = ls[r*256 + tid];
    if (tid < 64) ((float4*)dVdL)[tid] = ((const float4*)dVd)[tid];
    else if (tid < 128) ((float4*)lamL)[tid-64] = ((const float4*)lam)[tid-64];
  }

  // boundary w (f32 state in regs; lam stays in LDS)
  float w[64];
  #pragma unroll
  for (int kc = 0; kc < 8; ++kc)
    #pragma unroll
    for (int h = 0; h < 2; ++h){
      const int i = 32*kc + 16*h + 4*lh;
      const ushort4 wu = *(const ushort4*)(Wchk + ((size_t)ch*B_ + col)*D_ + i);
      const int e = 8*kc + 4*h;
      w[e+0]=bf2f(wu.x); w[e+1]=bf2f(wu.y); w[e+2]=bf2f(wu.z); w[e+3]=bf2f(wu.w);
    }

  // u prefetch for first step
  const size_t TS = (size_t)B_ * UD_;
  const float* Ucol = U + (size_t)col * UD_;
  float4 ua, ub, uc;
  {
    const float* Ut = Ucol + (size_t)(ch*8)*TS;
    ua = *(const float4*)&Ut[4*lh]; ub = *(const float4*)&Ut[16+4*lh]; uc = *(const float4*)&Ut[32+4*lh];
  }

  __syncthreads();   // the only block-wide barrier

  #pragma unroll 1
  for (int s = 0; s < 8; ++s){
    const int t = ch*8 + s;
    // build u fragments
    bf16x8 uf0, uf1;
    {
      union { ushort_t us[8]; bf16x8 v; } cv;
      cv.us[0]=f2bf(ua.x); cv.us[1]=f2bf(ua.y); cv.us[2]=f2bf(ua.z); cv.us[3]=f2bf(ua.w);
      cv.us[4]=f2bf(ub.x); cv.us[5]=f2bf(ub.y); cv.us[6]=f2bf(ub.z); cv.us[7]=f2bf(ub.w);
      uf0 = cv.v;
      cv.us[0]=f2bf(uc.x); cv.us[1]=f2bf(uc.y); cv.us[2]=f2bf(uc.z); cv.us[3]=f2bf(uc.w);
      cv.us[4]=0; cv.us[5]=0; cv.us[6]=0; cv.us[7]=0;
      uf1 = cv.v;
    }
    if (s < 7){
      const float* Ut = Ucol + (size_t)(t+1)*TS;
      ua = *(const float4*)&Ut[4*lh]; ub = *(const float4*)&Ut[16+4*lh]; uc = *(const float4*)&Ut[32+4*lh];
    }
    // scan step (lam from LDS)
    #pragma unroll
    for (int it = 0; it < 16; ++it){
      const bf16x8 a0 = *(const bf16x8*)&LwsL[((it*2+0)*64 + l)*8];
      const bf16x8 a1 = *(const bf16x8*)&LwsL[((it*2+1)*64 + l)*8];
      const float4 lv = *(const float4*)&lamL[32*(it>>1) + 16*(it&1) + 4*lh];
      f32x4 acc = {0.f,0.f,0.f,0.f};
      acc = mfma16(a0, uf0, acc);
      acc = mfma16(a1, uf1, acc);
      const int e0 = 8*(it>>1) + 4*(it&1);
      w[e0+0] = lv.x*w[e0+0] + acc[0];
      w[e0+1] = lv.y*w[e0+1] + acc[1];
      w[e0+2] = lv.z*w[e0+2] + acc[2];
      w[e0+3] = lv.w*w[e0+3] + acc[3];
    }
    // pack w fragments
    bf16x8 wfr[8];
    #pragma unroll
    for (int kc = 0; kc < 8; ++kc){
      union { ushort_t us[8]; bf16x8 v; } cv;
      #pragma unroll
      for (int j = 0; j < 8; ++j) cv.us[j] = f2bf(w[8*kc + j]);
      wfr[kc] = cv.v;
    }
    // Z strips: direct stores (lanes lh=0..3 give contiguous 64 B per batch row)
    float* zrow = outZ + ((size_t)t*B_ + col)*D_;
    #pragma unroll
    for (int mt = 0; mt < 16; ++mt){
      f32x4 acc = {0.f,0.f,0.f,0.f};
      #pragma unroll
      for (int kc = 0; kc < 8; ++kc){
        bf16x8 af;
        if (mt < 15) af = *(const bf16x8*)&AfL[((mt*8+kc)*64 + l)*8];
        else         af = *(const bf16x8*)(Af + ((size_t)((150+kc)*64 + l))*8);
        acc = mfma16(af, wfr[kc], acc);
      }
      const float4 dv = *(const float4*)&dVdL[mt*16 + 4*lh];
      acc[0] += dv.x * (float)wfr[mt>>1][0 + 4*(mt&1)];
      acc[1] += dv.y * (float)wfr[mt>>1][1 + 4*(mt&1)];
      acc[2] += dv.z * (float)wfr[mt>>1][2 + 4*(mt&1)];
      acc[3] += dv.w * (float)wfr[mt>>1][3 + 4*(mt&1)];
      *(float4*)&zrow[mt*16 + 4*lh] = make_float4(acc[0],acc[1],acc[2],acc[3]);
    }
    // Y strips (A-frags from global, L2-hot)
    float* yrow = outY + ((size_t)t*B_ + col)*NO_;
    #pragma unroll 1
    for (int my = 0; my < 5; ++my){
      const ushort_t* Ay = Af + (size_t)((16+my)*10)*512;
      f32x4 acc = {0.f,0.f,0.f,0.f};
      #pragma unroll
      for (int kc = 0; kc < 8; ++kc){
        const bf16x8 af = *(const bf16x8*)(Ay + (kc*64 + l)*8);
        acc = mfma16(af, wfr[kc], acc);
      }
      {
        const bf16x8 af8 = *(const bf16x8*)(Ay + (8*64 + l)*8);
        const bf16x8 af9 = *(const bf16x8*)(Ay + (9*64 + l)*8);
        acc = mfma16(af8, uf0, acc);
        acc = mfma16(af9, uf1, acc);
      }
      *(float4*)&yrow[my*16 + 4*lh] = make_float4(acc[0],acc[1],acc[2],acc[3]);
    }
  }
}

// ---------------- launcher ----------------
extern "C" void kernel_launch(void* const* d_in, const int* in_sizes, int n_in,
                              void* d_out, int out_size, void* d_ws, size_t ws_size,
                              hipStream_t stream){
  const float* z0  = (const float*)d_in[0];
  const float* dt  = (const float*)d_in[2];
  const float* U   = (const float*)d_in[3];
  const float* eig = (const float*)d_in[4];
  const float* V   = (const float*)d_in[5];
  const float* L   = (const float*)d_in[6];
  const float* C   = (const float*)d_in[7];
  const float* Dm  = (const float*)d_in[8];
  float* outZ = (float*)d_out;
  float* outY = outZ + (size_t)T_*B_*D_;

  char* ws = (char*)d_ws;
  float* Xa    = (float*)(ws + 0);        // later reused as VinvT
  float* Xb    = (float*)(ws + 262144);
  float* Tt    = (float*)(ws + 524288);
  float* Lw    = (float*)(ws + 786432);
  float* Cw    = (float*)(ws + 835584);
  float* lam   = (float*)(ws + 917504);
  float* dVd   = (float*)(ws + 918528);
  ushort_t* Af   = (ushort_t*)(ws + 919552);
  ushort_t* Lws  = (ushort_t*)(ws + 1134592);
  ushort_t* Wchk = (ushort_t*)(ws + 1167360);
  if (ws_size < 17944576u) return;

  k_init<<<256,256,0,stream>>>(V, eig, Xa, lam);
  // Newton-Schulz, 3 iters from X0 = 2I - V  -> Vinv = Xb
  k_mm_mul<<<256,256,0,stream>>>(V, Xa, Tt);
  k_mm_upd<<<256,256,0,stream>>>(Xa, Tt, Xb);
  k_mm_mul<<<256,256,0,stream>>>(V, Xb, Tt);
  k_mm_upd<<<256,256,0,stream>>>(Xb, Tt, Xa);
  k_mm_mul<<<256,256,0,stream>>>(V, Xa, Tt);
  k_mm_upd<<<256,256,0,stream>>>(Xa, Tt, Xb);
  k_prep1<<<592,256,0,stream>>>(Xb, V, L, C, dt, /*VinvT=*/Xa, Lw, Cw, dVd);
  k_prep2<<<288,256,0,stream>>>(z0, /*VinvT=*/Xa, Lw, Wchk, Lws);
  k_packA<<<210,64,0,stream>>>(V, Cw, Dm, dt, Af);
  k_scan<<<256,256,0,stream>>>(U, Lws, lam, Wchk);
  k_fused<<<512,256,0,stream>>>(U, Af, Lws, lam, dVd, Wchk, outZ, outY);
}

// Round 4
// 790.605 us; speedup vs baseline: 1.5061x; 1.1800x over previous
//
#include <hip/hip_runtime.h>

#define D_   256
#define UD_  48
#define NO_  80
#define T_   128
#define B_   2048

typedef __bf16 bf16x8 __attribute__((ext_vector_type(8)));
typedef float  f32x4  __attribute__((ext_vector_type(4)));
typedef unsigned short ushort_t;

static __device__ __forceinline__ ushort_t f2bf(float f){
  return __builtin_bit_cast(ushort_t, (__bf16)f);
}
static __device__ __forceinline__ float bf2f(ushort_t u){
  union { unsigned int i; float f; } c; c.i = ((unsigned int)u) << 16; return c.f;
}
static __device__ __forceinline__ f32x4 mfma16(bf16x8 a, bf16x8 b, f32x4 c){
  return __builtin_amdgcn_mfma_f32_16x16x32_bf16(a, b, c, 0, 0, 0);
}

// ---------------- prep ----------------

__global__ void k_init(const float* __restrict__ V, const float* __restrict__ eig,
                       float* __restrict__ Xa, float* __restrict__ lam){
  const int i = blockIdx.x, j = threadIdx.x;
  Xa[i*D_ + j] = (i == j ? 2.0f : 0.0f) - V[i*D_ + j];
  if (j == 0) lam[i] = 0.99f / (1.0f + expf(-eig[i]));
}

__global__ void k_mm_mul(const float* __restrict__ A, const float* __restrict__ B,
                         float* __restrict__ Cm){
  const int i = blockIdx.x, j = threadIdx.x;
  const float* Ar = A + i*D_;
  float a0=0.f,a1=0.f,a2=0.f,a3=0.f;
  #pragma unroll 4
  for (int k = 0; k < D_; k += 4){
    a0 += Ar[k+0] * B[(k+0)*D_ + j];
    a1 += Ar[k+1] * B[(k+1)*D_ + j];
    a2 += Ar[k+2] * B[(k+2)*D_ + j];
    a3 += Ar[k+3] * B[(k+3)*D_ + j];
  }
  Cm[i*D_ + j] = (a0+a1)+(a2+a3);
}

__global__ void k_mm_upd(const float* __restrict__ X, const float* __restrict__ Tm,
                         float* __restrict__ Xn){
  const int i = blockIdx.x, j = threadIdx.x;
  const float* Xr = X + i*D_;
  float a0=0.f,a1=0.f,a2=0.f,a3=0.f;
  #pragma unroll 4
  for (int k = 0; k < D_; k += 4){
    a0 += Xr[k+0] * Tm[(k+0)*D_ + j];
    a1 += Xr[k+1] * Tm[(k+1)*D_ + j];
    a2 += Xr[k+2] * Tm[(k+2)*D_ + j];
    a3 += Xr[k+3] * Tm[(k+3)*D_ + j];
  }
  Xn[i*D_ + j] = 2.0f*Xr[j] - ((a0+a1)+(a2+a3));
}

// VinvT = Vinv^T (+dVd); Lw = dt * Vinv @ L; Cw = C @ V
__global__ void k_prep1(const float* __restrict__ Vinv, const float* __restrict__ V,
                        const float* __restrict__ Lm, const float* __restrict__ Cmat,
                        const float* __restrict__ dt,
                        float* __restrict__ VinvT, float* __restrict__ Lw,
                        float* __restrict__ Cw, float* __restrict__ dVd){
  const int bid = blockIdx.x, tid = threadIdx.x;
  if (bid < 256){
    VinvT[tid*D_ + bid] = Vinv[bid*D_ + tid];
    if (tid == bid){ float v = V[bid*D_ + bid]; dVd[bid] = v - bf2f(f2bf(v)); }
  } else if (bid < 512){
    const int i = bid - 256;
    if (tid < UD_){
      float acc = 0.f;
      #pragma unroll 4
      for (int j = 0; j < D_; ++j) acc += Vinv[i*D_ + j] * Lm[j*UD_ + tid];
      Lw[i*UD_ + tid] = acc * dt[0];
    }
  } else {
    const int n = bid - 512;
    float acc = 0.f;
    #pragma unroll 4
    for (int j = 0; j < D_; ++j) acc += Cmat[n*D_ + j] * V[j*D_ + tid];
    Cw[n*D_ + tid] = acc;
  }
}

// w0 = z0 @ VinvT -> Wchk[0] (bf16), 8 rows/block; pack Lws A-fragments.
// k-map (bijective, A/B consistent): k = 32*kc + 4*lh + (j&3) + 16*(j>>2)
__global__ void k_prep2(const float* __restrict__ z0, const float* __restrict__ VinvT,
                        const float* __restrict__ Lw,
                        ushort_t* __restrict__ Wchk, ushort_t* __restrict__ Lws){
  __shared__ float zr[8][256];
  const int bid = blockIdx.x, tid = threadIdx.x;
  if (bid < 256){
    const int b0 = bid * 8;
    #pragma unroll
    for (int r = 0; r < 8; ++r) zr[r][tid] = z0[(size_t)(b0+r)*D_ + tid];
    __syncthreads();
    float acc[8] = {0.f,0.f,0.f,0.f,0.f,0.f,0.f,0.f};
    #pragma unroll 4
    for (int j = 0; j < D_; ++j){
      const float vj = VinvT[j*D_ + tid];
      #pragma unroll
      for (int r = 0; r < 8; ++r) acc[r] += zr[r][j] * vj;
    }
    #pragma unroll
    for (int r = 0; r < 8; ++r)
      Wchk[(size_t)(b0+r)*D_ + tid] = f2bf(acc[r]);
    return;
  }
  const int f = bid - 256;             // 0..31
  if (tid >= 64) return;
  const int l = tid, lm = l & 15, lh = l >> 4;
  const int it = f >> 1, kc2 = f & 1;
  const int ig = it*16 + lm;
  #pragma unroll
  for (int j = 0; j < 8; ++j){
    const int k = 32*kc2 + 4*lh + (j & 3) + 16*(j >> 2);
    Lws[(f*64 + l)*8 + j] = f2bf(k < UD_ ? Lw[ig*UD_ + k] : 0.f);
  }
}

// Pack augmented A fragments: rows 0..255 = V (Z), 256..335 = [Cw | dt*D] (Y). K=320.
__global__ void k_packA(const float* __restrict__ V, const float* __restrict__ Cw,
                        const float* __restrict__ Dmat, const float* __restrict__ dt,
                        ushort_t* __restrict__ Af){
  const int mt = blockIdx.x / 10, kc = blockIdx.x % 10;
  const int l = threadIdx.x, lm = l & 15, lh = l >> 4;
  const float dts = dt[0];
  #pragma unroll
  for (int j = 0; j < 8; ++j){
    const int k = 32*kc + 4*lh + (j & 3) + 16*(j >> 2);
    float val = 0.f;
    if (mt < 16){
      if (kc < 8) val = V[(mt*16 + lm)*D_ + k];
    } else {
      const int n = (mt - 16)*16 + lm;
      if (kc < 8) val = Cw[n*D_ + k];
      else { const int ku = k - 256; if (ku < UD_) val = dts * Dmat[n*UD_ + ku]; }
    }
    Af[((size_t)(mt*10 + kc)*64 + l)*8 + j] = f2bf(val);
  }
}

// ---------------- phase 1: boundary scan (barrier-free, 2-deep prefetch) ----------------
#define SCAN_STEP(UA, UB, UC, TT) do {                                          \
  union { ushort_t us[8]; bf16x8 v; } c0, c1;                                   \
  c0.us[0]=f2bf((UA).x); c0.us[1]=f2bf((UA).y); c0.us[2]=f2bf((UA).z); c0.us[3]=f2bf((UA).w); \
  c0.us[4]=f2bf((UB).x); c0.us[5]=f2bf((UB).y); c0.us[6]=f2bf((UB).z); c0.us[7]=f2bf((UB).w); \
  c1.us[0]=f2bf((UC).x); c1.us[1]=f2bf((UC).y); c1.us[2]=f2bf((UC).z); c1.us[3]=f2bf((UC).w); \
  c1.us[4]=0; c1.us[5]=0; c1.us[6]=0; c1.us[7]=0;                               \
  _Pragma("unroll")                                                             \
  for (int q = 0; q < 2; ++q){                                                  \
    f32x4 acc = {0.f,0.f,0.f,0.f};                                              \
    acc = mfma16(lwf[q*2+0], c0.v, acc);                                        \
    acc = mfma16(lwf[q*2+1], c1.v, acc);                                        \
    _Pragma("unroll")                                                           \
    for (int r = 0; r < 4; ++r) w[q*4+r] = lamr[q*4+r]*w[q*4+r] + acc[r];       \
  }                                                                             \
  if ((((TT) & 7) == 7) && ((TT) < T_-1)){                                      \
    const int c2 = ((TT)+1) >> 3;                                               \
    _Pragma("unroll")                                                           \
    for (int q = 0; q < 2; ++q){                                                \
      const int i = (itb+q)*16 + 4*lh;                                          \
      ushort4 o; o.x=f2bf(w[q*4+0]); o.y=f2bf(w[q*4+1]); o.z=f2bf(w[q*4+2]); o.w=f2bf(w[q*4+3]); \
      *(ushort4*)(Wchk + ((size_t)c2*B_ + row)*D_ + i) = o;                     \
    }                                                                           \
  }                                                                             \
} while(0)

__global__ void __launch_bounds__(256) k_scan(const float* __restrict__ U,
    const ushort_t* __restrict__ Lws, const float* __restrict__ lam,
    ushort_t* __restrict__ Wchk){
  const int tid = threadIdx.x;
  const int wid = tid >> 6, l = tid & 63;
  const int lm = l & 15, lh = l >> 4;
  const int bq = blockIdx.x >> 1, ih = blockIdx.x & 1;
  const int b0 = bq * 16;
  const int row = b0 + lm;
  const int itb = ih*8 + wid*2;

  bf16x8 lwf[4];
  #pragma unroll
  for (int q = 0; q < 2; ++q)
    #pragma unroll
    for (int c = 0; c < 2; ++c)
      lwf[q*2 + c] = *(const bf16x8*)(Lws + ((size_t)(((itb+q)*2 + c)*64 + l))*8);

  float lamr[8], w[8];
  #pragma unroll
  for (int q = 0; q < 2; ++q){
    const int i = (itb+q)*16 + 4*lh;
    const float4 lv = *(const float4*)&lam[i];
    const ushort4 wu = *(const ushort4*)(Wchk + (size_t)row*D_ + i);
    lamr[q*4+0]=lv.x; lamr[q*4+1]=lv.y; lamr[q*4+2]=lv.z; lamr[q*4+3]=lv.w;
    w[q*4+0]=bf2f(wu.x); w[q*4+1]=bf2f(wu.y); w[q*4+2]=bf2f(wu.z); w[q*4+3]=bf2f(wu.w);
  }

  const size_t TS = (size_t)B_ * UD_;
  const float* Urow = U + (size_t)row * UD_;
  float4 Aa, Ab, Ac, Ba, Bb, Bc;
  Aa = *(const float4*)&Urow[4*lh]; Ab = *(const float4*)&Urow[16+4*lh]; Ac = *(const float4*)&Urow[32+4*lh];
  { const float* Up = Urow + TS;
    Ba = *(const float4*)&Up[4*lh]; Bb = *(const float4*)&Up[16+4*lh]; Bc = *(const float4*)&Up[32+4*lh]; }

  #pragma unroll 1
  for (int tt = 0; tt < 64; ++tt){
    const int t0 = 2*tt;
    SCAN_STEP(Aa, Ab, Ac, t0);
    if (t0 + 2 < T_){
      const float* Up = Urow + (size_t)(t0+2)*TS;
      Aa = *(const float4*)&Up[4*lh]; Ab = *(const float4*)&Up[16+4*lh]; Ac = *(const float4*)&Up[32+4*lh];
    }
    SCAN_STEP(Ba, Bb, Bc, t0+1);
    if (t0 + 3 < T_){
      const float* Up = Urow + (size_t)(t0+3)*TS;
      Ba = *(const float4*)&Up[4*lh]; Bb = *(const float4*)&Up[16+4*lh]; Bc = *(const float4*)&Up[32+4*lh];
    }
  }
}

// ---------------- fused replay + output GEMM (barrier-free, coalesced stores) ----------------
// 512 blocks = 32 bq(64 rows) x 16 ch; 256 thr = 4 waves; wave owns 16 rows.
// Af fragments read from global (215 KB, L2-resident chip-wide) - no block staging.
// Per-WAVE LDS transpose buffers make every global store cover full 128 B lines
// (round-3 counters showed 64 B-chunk stores caused ~600 MB of write-allocate RMW fetch).
// LDS total 73728 B -> 2 blocks/CU (8 waves/CU) at VGPR=256.
__global__ void __launch_bounds__(256) k_fused(
    const float* __restrict__ U, const ushort_t* __restrict__ Af,
    const ushort_t* __restrict__ Lws, const float* __restrict__ lam,
    const float* __restrict__ dVd, const ushort_t* __restrict__ Wchk,
    float* __restrict__ outZ, float* __restrict__ outY){
  __shared__ __align__(16) ushort_t LwsL[32*512];     // 32768 B
  __shared__ __align__(16) float    trbZ[4][16][68];  // 17408 B (stride 68: 16B-aligned f4)
  __shared__ __align__(16) float    trbY[4][16][84];  // 21504 B
  __shared__ __align__(16) float    dVdL[256];        // 1024 B
  __shared__ __align__(16) float    lamL[256];        // 1024 B

  const int tid = threadIdx.x;
  const int ch = blockIdx.x & 15;
  const int bq = blockIdx.x >> 4;
  const int wid = tid >> 6, l = tid & 63;
  const int lm = l & 15, lh = l >> 4;
  const int col0 = bq*64 + wid*16;
  const int col = col0 + lm;

  // one-time staging
  {
    const uint4* ls = (const uint4*)Lws;
    uint4* ld = (uint4*)LwsL;
    #pragma unroll
    for (int r = 0; r < 8; ++r) ld[r*256 + tid] = ls[r*256 + tid];
    if (tid < 64) ((float4*)dVdL)[tid] = ((const float4*)dVd)[tid];
    else if (tid < 128) ((float4*)lamL)[tid-64] = ((const float4*)lam)[tid-64];
  }

  // boundary w (f32 state in regs)
  float w[64];
  #pragma unroll
  for (int kc = 0; kc < 8; ++kc)
    #pragma unroll
    for (int h = 0; h < 2; ++h){
      const int i = 32*kc + 16*h + 4*lh;
      const ushort4 wu = *(const ushort4*)(Wchk + ((size_t)ch*B_ + col)*D_ + i);
      const int e = 8*kc + 4*h;
      w[e+0]=bf2f(wu.x); w[e+1]=bf2f(wu.y); w[e+2]=bf2f(wu.z); w[e+3]=bf2f(wu.w);
    }

  // u prefetch for first step
  const size_t TS = (size_t)B_ * UD_;
  const float* Ucol = U + (size_t)col * UD_;
  float4 ua, ub, uc;
  {
    const float* Ut = Ucol + (size_t)(ch*8)*TS;
    ua = *(const float4*)&Ut[4*lh]; ub = *(const float4*)&Ut[16+4*lh]; uc = *(const float4*)&Ut[32+4*lh];
  }

  __syncthreads();   // the only block-wide barrier (LwsL/lamL/dVdL ready)

  #pragma unroll 1
  for (int s = 0; s < 8; ++s){
    const int t = ch*8 + s;
    // build u fragments
    bf16x8 uf0, uf1;
    {
      union { ushort_t us[8]; bf16x8 v; } cv;
      cv.us[0]=f2bf(ua.x); cv.us[1]=f2bf(ua.y); cv.us[2]=f2bf(ua.z); cv.us[3]=f2bf(ua.w);
      cv.us[4]=f2bf(ub.x); cv.us[5]=f2bf(ub.y); cv.us[6]=f2bf(ub.z); cv.us[7]=f2bf(ub.w);
      uf0 = cv.v;
      cv.us[0]=f2bf(uc.x); cv.us[1]=f2bf(uc.y); cv.us[2]=f2bf(uc.z); cv.us[3]=f2bf(uc.w);
      cv.us[4]=0; cv.us[5]=0; cv.us[6]=0; cv.us[7]=0;
      uf1 = cv.v;
    }
    if (s < 7){
      const float* Ut = Ucol + (size_t)(t+1)*TS;
      ua = *(const float4*)&Ut[4*lh]; ub = *(const float4*)&Ut[16+4*lh]; uc = *(const float4*)&Ut[32+4*lh];
    }
    // scan step (lam from LDS)
    #pragma unroll
    for (int it = 0; it < 16; ++it){
      const bf16x8 a0 = *(const bf16x8*)&LwsL[((it*2+0)*64 + l)*8];
      const bf16x8 a1 = *(const bf16x8*)&LwsL[((it*2+1)*64 + l)*8];
      const float4 lv = *(const float4*)&lamL[32*(it>>1) + 16*(it&1) + 4*lh];
      f32x4 acc = {0.f,0.f,0.f,0.f};
      acc = mfma16(a0, uf0, acc);
      acc = mfma16(a1, uf1, acc);
      const int e0 = 8*(it>>1) + 4*(it&1);
      w[e0+0] = lv.x*w[e0+0] + acc[0];
      w[e0+1] = lv.y*w[e0+1] + acc[1];
      w[e0+2] = lv.z*w[e0+2] + acc[2];
      w[e0+3] = lv.w*w[e0+3] + acc[3];
    }
    // pack w fragments
    bf16x8 wfr[8];
    #pragma unroll
    for (int kc = 0; kc < 8; ++kc){
      union { ushort_t us[8]; bf16x8 v; } cv;
      #pragma unroll
      for (int j = 0; j < 8; ++j) cv.us[j] = f2bf(w[8*kc + j]);
      wfr[kc] = cv.v;
    }
    // Z: 4 groups of 4 strips; per-wave LDS transpose -> full-line stores
    float* zbase = outZ + ((size_t)t*B_ + col0)*D_;
    #pragma unroll
    for (int g = 0; g < 4; ++g){
      #pragma unroll
      for (int mi = 0; mi < 4; ++mi){
        const int mt = g*4 + mi;
        f32x4 acc = {0.f,0.f,0.f,0.f};
        #pragma unroll
        for (int kc = 0; kc < 8; ++kc){
          const bf16x8 af = *(const bf16x8*)(Af + ((size_t)(mt*8 + kc) + (size_t)mt*2)*512 + (size_t)l*8);
          acc = mfma16(af, wfr[kc], acc);
        }
        const float4 dv = *(const float4*)&dVdL[mt*16 + 4*lh];
        acc[0] += dv.x * (float)wfr[mt>>1][0 + 4*(mt&1)];
        acc[1] += dv.y * (float)wfr[mt>>1][1 + 4*(mt&1)];
        acc[2] += dv.z * (float)wfr[mt>>1][2 + 4*(mt&1)];
        acc[3] += dv.w * (float)wfr[mt>>1][3 + 4*(mt&1)];
        *(float4*)&trbZ[wid][lm][mi*16 + 4*lh] = make_float4(acc[0],acc[1],acc[2],acc[3]);
      }
      __builtin_amdgcn_wave_barrier();
      #pragma unroll
      for (int j = 0; j < 4; ++j){
        const int r_ = j*4 + (l >> 4), c16 = l & 15;
        const float4 v = *(const float4*)&trbZ[wid][r_][4*c16];
        *(float4*)&zbase[(size_t)r_*D_ + g*64 + 4*c16] = v;
      }
      __builtin_amdgcn_wave_barrier();
    }
    // Y: 5 strips; per-wave LDS transpose -> contiguous 5 KB per wave
    #pragma unroll
    for (int my = 0; my < 5; ++my){
      const ushort_t* Ay = Af + (size_t)((16+my)*10)*512;
      f32x4 acc = {0.f,0.f,0.f,0.f};
      #pragma unroll
      for (int kc = 0; kc < 8; ++kc){
        const bf16x8 af = *(const bf16x8*)(Ay + (kc*64 + l)*8);
        acc = mfma16(af, wfr[kc], acc);
      }
      {
        const bf16x8 af8 = *(const bf16x8*)(Ay + (8*64 + l)*8);
        const bf16x8 af9 = *(const bf16x8*)(Ay + (9*64 + l)*8);
        acc = mfma16(af8, uf0, acc);
        acc = mfma16(af9, uf1, acc);
      }
      *(float4*)&trbY[wid][lm][my*16 + 4*lh] = make_float4(acc[0],acc[1],acc[2],acc[3]);
    }
    __builtin_amdgcn_wave_barrier();
    {
      float* ybase = outY + ((size_t)t*B_ + col0)*NO_;
      #pragma unroll
      for (int j = 0; j < 5; ++j){
        const int idx = j*64 + l;
        const int r_ = idx / 20, c20 = idx % 20;
        const float4 v = *(const float4*)&trbY[wid][r_][4*c20];
        *(float4*)&ybase[(size_t)idx*4] = v;
      }
    }
    __builtin_amdgcn_wave_barrier();
  }
}

// ---------------- launcher ----------------
extern "C" void kernel_launch(void* const* d_in, const int* in_sizes, int n_in,
                              void* d_out, int out_size, void* d_ws, size_t ws_size,
                              hipStream_t stream){
  const float* z0  = (const float*)d_in[0];
  const float* dt  = (const float*)d_in[2];
  const float* U   = (const float*)d_in[3];
  const float* eig = (const float*)d_in[4];
  const float* V   = (const float*)d_in[5];
  const float* L   = (const float*)d_in[6];
  const float* C   = (const float*)d_in[7];
  const float* Dm  = (const float*)d_in[8];
  float* outZ = (float*)d_out;
  float* outY = outZ + (size_t)T_*B_*D_;

  char* ws = (char*)d_ws;
  float* Xa    = (float*)(ws + 0);        // later reused as VinvT
  float* Xb    = (float*)(ws + 262144);
  float* Tt    = (float*)(ws + 524288);
  float* Lw    = (float*)(ws + 786432);
  float* Cw    = (float*)(ws + 835584);
  float* lam   = (float*)(ws + 917504);
  float* dVd   = (float*)(ws + 918528);
  ushort_t* Af   = (ushort_t*)(ws + 919552);
  ushort_t* Lws  = (ushort_t*)(ws + 1134592);
  ushort_t* Wchk = (ushort_t*)(ws + 1167360);
  if (ws_size < 17944576u) return;

  k_init<<<256,256,0,stream>>>(V, eig, Xa, lam);
  // Newton-Schulz, 3 iters from X0 = 2I - V  -> Vinv = Xb
  k_mm_mul<<<256,256,0,stream>>>(V, Xa, Tt);
  k_mm_upd<<<256,256,0,stream>>>(Xa, Tt, Xb);
  k_mm_mul<<<256,256,0,stream>>>(V, Xb, Tt);
  k_mm_upd<<<256,256,0,stream>>>(Xb, Tt, Xa);
  k_mm_mul<<<256,256,0,stream>>>(V, Xa, Tt);
  k_mm_upd<<<256,256,0,stream>>>(Xa, Tt, Xb);
  k_prep1<<<592,256,0,stream>>>(Xb, V, L, C, dt, /*VinvT=*/Xa, Lw, Cw, dVd);
  k_prep2<<<288,256,0,stream>>>(z0, /*VinvT=*/Xa, Lw, Wchk, Lws);
  k_packA<<<210,64,0,stream>>>(V, Cw, Dm, dt, Af);
  k_scan<<<256,256,0,stream>>>(U, Lws, lam, Wchk);
  k_fused<<<512,256,0,stream>>>(U, Af, Lws, lam, dVd, Wchk, outZ, outY);
}

// Round 5
// 267.828 us; speedup vs baseline: 4.4459x; 2.9519x over previous
//
#include <hip/hip_runtime.h>

#define D_   256
#define UD_  48
#define NO_  80
#define T_   128
#define B_   2048

typedef __bf16 bf16x8 __attribute__((ext_vector_type(8)));
typedef float  f32x4  __attribute__((ext_vector_type(4)));
typedef unsigned short ushort_t;

static __device__ __forceinline__ ushort_t f2bf(float f){
  return __builtin_bit_cast(ushort_t, (__bf16)f);
}
static __device__ __forceinline__ float bf2f(ushort_t u){
  union { unsigned int i; float f; } c; c.i = ((unsigned int)u) << 16; return c.f;
}
static __device__ __forceinline__ f32x4 mfma16(bf16x8 a, bf16x8 b, f32x4 c){
  return __builtin_amdgcn_mfma_f32_16x16x32_bf16(a, b, c, 0, 0, 0);
}

// ---------------- prep ----------------

__global__ void k_init(const float* __restrict__ V, const float* __restrict__ eig,
                       float* __restrict__ Xa, float* __restrict__ lam){
  const int i = blockIdx.x, j = threadIdx.x;
  Xa[i*D_ + j] = (i == j ? 2.0f : 0.0f) - V[i*D_ + j];
  if (j == 0) lam[i] = 0.99f / (1.0f + expf(-eig[i]));
}

__global__ void k_mm_mul(const float* __restrict__ A, const float* __restrict__ B,
                         float* __restrict__ Cm){
  const int i = blockIdx.x, j = threadIdx.x;
  const float* Ar = A + i*D_;
  float a0=0.f,a1=0.f,a2=0.f,a3=0.f;
  #pragma unroll 4
  for (int k = 0; k < D_; k += 4){
    a0 += Ar[k+0] * B[(k+0)*D_ + j];
    a1 += Ar[k+1] * B[(k+1)*D_ + j];
    a2 += Ar[k+2] * B[(k+2)*D_ + j];
    a3 += Ar[k+3] * B[(k+3)*D_ + j];
  }
  Cm[i*D_ + j] = (a0+a1)+(a2+a3);
}

__global__ void k_mm_upd(const float* __restrict__ X, const float* __restrict__ Tm,
                         float* __restrict__ Xn){
  const int i = blockIdx.x, j = threadIdx.x;
  const float* Xr = X + i*D_;
  float a0=0.f,a1=0.f,a2=0.f,a3=0.f;
  #pragma unroll 4
  for (int k = 0; k < D_; k += 4){
    a0 += Xr[k+0] * Tm[(k+0)*D_ + j];
    a1 += Xr[k+1] * Tm[(k+1)*D_ + j];
    a2 += Xr[k+2] * Tm[(k+2)*D_ + j];
    a3 += Xr[k+3] * Tm[(k+3)*D_ + j];
  }
  Xn[i*D_ + j] = 2.0f*Xr[j] - ((a0+a1)+(a2+a3));
}

// VinvT = Vinv^T (+dVd); Lw = dt * Vinv @ L; Cw = C @ V
__global__ void k_prep1(const float* __restrict__ Vinv, const float* __restrict__ V,
                        const float* __restrict__ Lm, const float* __restrict__ Cmat,
                        const float* __restrict__ dt,
                        float* __restrict__ VinvT, float* __restrict__ Lw,
                        float* __restrict__ Cw, float* __restrict__ dVd){
  const int bid = blockIdx.x, tid = threadIdx.x;
  if (bid < 256){
    VinvT[tid*D_ + bid] = Vinv[bid*D_ + tid];
    if (tid == bid){ float v = V[bid*D_ + bid]; dVd[bid] = v - bf2f(f2bf(v)); }
  } else if (bid < 512){
    const int i = bid - 256;
    if (tid < UD_){
      float acc = 0.f;
      #pragma unroll 4
      for (int j = 0; j < D_; ++j) acc += Vinv[i*D_ + j] * Lm[j*UD_ + tid];
      Lw[i*UD_ + tid] = acc * dt[0];
    }
  } else {
    const int n = bid - 512;
    float acc = 0.f;
    #pragma unroll 4
    for (int j = 0; j < D_; ++j) acc += Cmat[n*D_ + j] * V[j*D_ + tid];
    Cw[n*D_ + tid] = acc;
  }
}

// w0 = z0 @ VinvT -> Wchk[0] (bf16), 8 rows/block; pack Lws A-fragments.
// k-map (bijective, A/B consistent): k = 32*kc + 4*lh + (j&3) + 16*(j>>2)
__global__ void k_prep2(const float* __restrict__ z0, const float* __restrict__ VinvT,
                        const float* __restrict__ Lw,
                        ushort_t* __restrict__ Wchk, ushort_t* __restrict__ Lws){
  __shared__ float zr[8][256];
  const int bid = blockIdx.x, tid = threadIdx.x;
  if (bid < 256){
    const int b0 = bid * 8;
    #pragma unroll
    for (int r = 0; r < 8; ++r) zr[r][tid] = z0[(size_t)(b0+r)*D_ + tid];
    __syncthreads();
    float acc[8] = {0.f,0.f,0.f,0.f,0.f,0.f,0.f,0.f};
    #pragma unroll 4
    for (int j = 0; j < D_; ++j){
      const float vj = VinvT[j*D_ + tid];
      #pragma unroll
      for (int r = 0; r < 8; ++r) acc[r] += zr[r][j] * vj;
    }
    #pragma unroll
    for (int r = 0; r < 8; ++r)
      Wchk[(size_t)(b0+r)*D_ + tid] = f2bf(acc[r]);
    return;
  }
  const int f = bid - 256;             // 0..31
  if (tid >= 64) return;
  const int l = tid, lm = l & 15, lh = l >> 4;
  const int it = f >> 1, kc2 = f & 1;
  const int ig = it*16 + lm;
  #pragma unroll
  for (int j = 0; j < 8; ++j){
    const int k = 32*kc2 + 4*lh + (j & 3) + 16*(j >> 2);
    Lws[(f*64 + l)*8 + j] = f2bf(k < UD_ ? Lw[ig*UD_ + k] : 0.f);
  }
}

// Pack augmented A fragments: rows 0..255 = V (Z), 256..335 = [Cw | dt*D] (Y). K=320.
__global__ void k_packA(const float* __restrict__ V, const float* __restrict__ Cw,
                        const float* __restrict__ Dmat, const float* __restrict__ dt,
                        ushort_t* __restrict__ Af){
  const int mt = blockIdx.x / 10, kc = blockIdx.x % 10;
  const int l = threadIdx.x, lm = l & 15, lh = l >> 4;
  const float dts = dt[0];
  #pragma unroll
  for (int j = 0; j < 8; ++j){
    const int k = 32*kc + 4*lh + (j & 3) + 16*(j >> 2);
    float val = 0.f;
    if (mt < 16){
      if (kc < 8) val = V[(mt*16 + lm)*D_ + k];
    } else {
      const int n = (mt - 16)*16 + lm;
      if (kc < 8) val = Cw[n*D_ + k];
      else { const int ku = k - 256; if (ku < UD_) val = dts * Dmat[n*UD_ + ku]; }
    }
    Af[((size_t)(mt*10 + kc)*64 + l)*8 + j] = f2bf(val);
  }
}

// ---------------- phase 1: boundary scan (barrier-free, 2-deep prefetch) ----------------
#define SCAN_STEP(UA, UB, UC, TT) do {                                          \
  union { ushort_t us[8]; bf16x8 v; } c0, c1;                                   \
  c0.us[0]=f2bf((UA).x); c0.us[1]=f2bf((UA).y); c0.us[2]=f2bf((UA).z); c0.us[3]=f2bf((UA).w); \
  c0.us[4]=f2bf((UB).x); c0.us[5]=f2bf((UB).y); c0.us[6]=f2bf((UB).z); c0.us[7]=f2bf((UB).w); \
  c1.us[0]=f2bf((UC).x); c1.us[1]=f2bf((UC).y); c1.us[2]=f2bf((UC).z); c1.us[3]=f2bf((UC).w); \
  c1.us[4]=0; c1.us[5]=0; c1.us[6]=0; c1.us[7]=0;                               \
  _Pragma("unroll")                                                             \
  for (int q = 0; q < 2; ++q){                                                  \
    f32x4 acc = {0.f,0.f,0.f,0.f};                                              \
    acc = mfma16(lwf[q*2+0], c0.v, acc);                                        \
    acc = mfma16(lwf[q*2+1], c1.v, acc);                                        \
    _Pragma("unroll")                                                           \
    for (int r = 0; r < 4; ++r) w[q*4+r] = lamr[q*4+r]*w[q*4+r] + acc[r];       \
  }                                                                             \
  if ((((TT) & 7) == 7) && ((TT) < T_-1)){                                      \
    const int c2 = ((TT)+1) >> 3;                                               \
    _Pragma("unroll")                                                           \
    for (int q = 0; q < 2; ++q){                                                \
      const int i = (itb+q)*16 + 4*lh;                                          \
      ushort4 o; o.x=f2bf(w[q*4+0]); o.y=f2bf(w[q*4+1]); o.z=f2bf(w[q*4+2]); o.w=f2bf(w[q*4+3]); \
      *(ushort4*)(Wchk + ((size_t)c2*B_ + row)*D_ + i) = o;                     \
    }                                                                           \
  }                                                                             \
} while(0)

__global__ void __launch_bounds__(256) k_scan(const float* __restrict__ U,
    const ushort_t* __restrict__ Lws, const float* __restrict__ lam,
    ushort_t* __restrict__ Wchk){
  const int tid = threadIdx.x;
  const int wid = tid >> 6, l = tid & 63;
  const int lm = l & 15, lh = l >> 4;
  const int bq = blockIdx.x >> 1, ih = blockIdx.x & 1;
  const int b0 = bq * 16;
  const int row = b0 + lm;
  const int itb = ih*8 + wid*2;

  bf16x8 lwf[4];
  #pragma unroll
  for (int q = 0; q < 2; ++q)
    #pragma unroll
    for (int c = 0; c < 2; ++c)
      lwf[q*2 + c] = *(const bf16x8*)(Lws + ((size_t)(((itb+q)*2 + c)*64 + l))*8);

  float lamr[8], w[8];
  #pragma unroll
  for (int q = 0; q < 2; ++q){
    const int i = (itb+q)*16 + 4*lh;
    const float4 lv = *(const float4*)&lam[i];
    const ushort4 wu = *(const ushort4*)(Wchk + (size_t)row*D_ + i);
    lamr[q*4+0]=lv.x; lamr[q*4+1]=lv.y; lamr[q*4+2]=lv.z; lamr[q*4+3]=lv.w;
    w[q*4+0]=bf2f(wu.x); w[q*4+1]=bf2f(wu.y); w[q*4+2]=bf2f(wu.z); w[q*4+3]=bf2f(wu.w);
  }

  const size_t TS = (size_t)B_ * UD_;
  const float* Urow = U + (size_t)row * UD_;
  float4 Aa, Ab, Ac, Ba, Bb, Bc;
  Aa = *(const float4*)&Urow[4*lh]; Ab = *(const float4*)&Urow[16+4*lh]; Ac = *(const float4*)&Urow[32+4*lh];
  { const float* Up = Urow + TS;
    Ba = *(const float4*)&Up[4*lh]; Bb = *(const float4*)&Up[16+4*lh]; Bc = *(const float4*)&Up[32+4*lh]; }

  #pragma unroll 1
  for (int tt = 0; tt < 64; ++tt){
    const int t0 = 2*tt;
    SCAN_STEP(Aa, Ab, Ac, t0);
    if (t0 + 2 < T_){
      const float* Up = Urow + (size_t)(t0+2)*TS;
      Aa = *(const float4*)&Up[4*lh]; Ab = *(const float4*)&Up[16+4*lh]; Ac = *(const float4*)&Up[32+4*lh];
    }
    SCAN_STEP(Ba, Bb, Bc, t0+1);
    if (t0 + 3 < T_){
      const float* Up = Urow + (size_t)(t0+3)*TS;
      Ba = *(const float4*)&Up[4*lh]; Bb = *(const float4*)&Up[16+4*lh]; Bc = *(const float4*)&Up[32+4*lh];
    }
  }
}

// ---------------- fused replay + output GEMM ----------------
// 1024 blocks = 2 h(z-col halves) x 32 bq(64 rows) x 16 ch; 256 thr = 4 waves.
// ALL GEMM operands LDS-resident (one-shot staging): AfZ-half 64K + AfY-part 30K +
// Lws 32K + trbZ 17K + dVd/lam = 147968 B. Scan duplicated per half (cheap: MFMA
// is ~9us total at peak). No per-step barriers, no per-step global A reads
// (round-4 counters: per-step Af global reads missed L2 ~100% -> 830 MB fetch).
// VGPR=256 => 4 waves/CU (r0/r3/r4 evidence); loop latencies are only prefetched
// u loads and fire-and-forget stores.
__global__ void __launch_bounds__(256) k_fused(
    const float* __restrict__ U, const ushort_t* __restrict__ Af,
    const ushort_t* __restrict__ Lws, const float* __restrict__ lam,
    const float* __restrict__ dVd, const ushort_t* __restrict__ Wchk,
    float* __restrict__ outZ, float* __restrict__ outY){
  __shared__ __align__(16) ushort_t AfZhL[8*8*512];   // 65536 B  (8 strips x 8 kc)
  __shared__ __align__(16) ushort_t LwsL[32*512];     // 32768 B
  __shared__ __align__(16) ushort_t AfYhL[30*512];    // 30720 B  (h0:3 strips, h1:2)
  __shared__ __align__(16) float    trbZ[4][16][68];  // 17408 B
  __shared__ __align__(16) float    dVdL[128];        // 512 B   (half)
  __shared__ __align__(16) float    lamL[256];        // 1024 B

  const int tid = threadIdx.x;
  const int bid = blockIdx.x;
  const int h  = bid >> 9;            // 0,1: z-col half
  const int ch = bid & 15;
  const int bq = (bid >> 4) & 31;
  const int wid = tid >> 6, l = tid & 63;
  const int lm = l & 15, lh = l >> 4;
  const int col0 = bq*64 + wid*16;
  const int col = col0 + lm;

  // ---- one-time staging ----
  {
    const uint4* gsrc = (const uint4*)Af;
    uint4* dz = (uint4*)AfZhL;
    #pragma unroll
    for (int r = 0; r < 16; ++r){
      const int i = r*256 + tid;            // 0..4095
      const int f = i >> 6, l4 = i & 63;    // f = mi8*8+kc
      const int mi8 = f >> 3, kc = f & 7;
      dz[i] = gsrc[(size_t)((h*8 + mi8)*10 + kc)*64 + l4];
    }
    uint4* dy = (uint4*)AfYhL;
    const int nY = h ? 1280 : 1920;
    const int sb = 16 + (h ? 3 : 0);
    #pragma unroll
    for (int r = 0; r < 8; ++r){
      const int i = r*256 + tid;
      if (i < nY){
        const int f = i >> 6, l4 = i & 63;  // f = myl*10 + j
        const int myl = f / 10, j = f % 10;
        dy[i] = gsrc[(size_t)((sb + myl)*10 + j)*64 + l4];
      }
    }
    const uint4* ls = (const uint4*)Lws;
    uint4* ld = (uint4*)LwsL;
    #pragma unroll
    for (int r = 0; r < 8; ++r) ld[r*256 + tid] = ls[r*256 + tid];
    if (tid < 32) ((float4*)dVdL)[tid] = ((const float4*)(dVd + h*128))[tid];
    else if (tid < 96) ((float4*)lamL)[tid-32] = ((const float4*)lam)[tid-32];
  }

  // boundary w (f32 state in regs)
  float w[64];
  #pragma unroll
  for (int kc = 0; kc < 8; ++kc)
    #pragma unroll
    for (int hh = 0; hh < 2; ++hh){
      const int i = 32*kc + 16*hh + 4*lh;
      const ushort4 wu = *(const ushort4*)(Wchk + ((size_t)ch*B_ + col)*D_ + i);
      const int e = 8*kc + 4*hh;
      w[e+0]=bf2f(wu.x); w[e+1]=bf2f(wu.y); w[e+2]=bf2f(wu.z); w[e+3]=bf2f(wu.w);
    }

  // u prefetch for first step
  const size_t TS = (size_t)B_ * UD_;
  const float* Ucol = U + (size_t)col * UD_;
  float4 ua, ub, uc;
  {
    const float* Ut = Ucol + (size_t)(ch*8)*TS;
    ua = *(const float4*)&Ut[4*lh]; ub = *(const float4*)&Ut[16+4*lh]; uc = *(const float4*)&Ut[32+4*lh];
  }

  __syncthreads();   // the only block-wide barrier

#define ZLOOP(HH)                                                               \
  { float* zbase = outZ + ((size_t)t*B_ + col0)*D_ + (HH)*128;                  \
    _Pragma("unroll")                                                           \
    for (int g = 0; g < 2; ++g){                                                \
      _Pragma("unroll")                                                         \
      for (int mi = 0; mi < 4; ++mi){                                           \
        const int mi8 = g*4 + mi;                                               \
        f32x4 acc = {0.f,0.f,0.f,0.f};                                          \
        _Pragma("unroll")                                                       \
        for (int kc = 0; kc < 8; ++kc){                                         \
          const bf16x8 af = *(const bf16x8*)&AfZhL[((mi8*8+kc)*64 + l)*8];      \
          acc = mfma16(af, wfr[kc], acc);                                       \
        }                                                                       \
        const float4 dv = *(const float4*)&dVdL[mi8*16 + 4*lh];                 \
        acc[0] += dv.x * (float)wfr[((HH)*8+mi8)>>1][0 + 4*(mi8&1)];            \
        acc[1] += dv.y * (float)wfr[((HH)*8+mi8)>>1][1 + 4*(mi8&1)];            \
        acc[2] += dv.z * (float)wfr[((HH)*8+mi8)>>1][2 + 4*(mi8&1)];            \
        acc[3] += dv.w * (float)wfr[((HH)*8+mi8)>>1][3 + 4*(mi8&1)];            \
        *(float4*)&trbZ[wid][lm][mi*16 + 4*lh] = make_float4(acc[0],acc[1],acc[2],acc[3]); \
      }                                                                         \
      __builtin_amdgcn_wave_barrier();                                          \
      _Pragma("unroll")                                                         \
      for (int j = 0; j < 4; ++j){                                              \
        const int r_ = j*4 + (l >> 4), c16 = l & 15;                            \
        const float4 v = *(const float4*)&trbZ[wid][r_][4*c16];                 \
        *(float4*)&zbase[(size_t)r_*D_ + g*64 + 4*c16] = v;                     \
      }                                                                         \
      __builtin_amdgcn_wave_barrier();                                          \
    } }

#define YLOOP(COFF, NMY)                                                        \
  { float* yrow = outY + ((size_t)t*B_ + col)*NO_ + (COFF);                     \
    _Pragma("unroll")                                                           \
    for (int my = 0; my < (NMY); ++my){                                         \
      f32x4 acc = {0.f,0.f,0.f,0.f};                                            \
      _Pragma("unroll")                                                         \
      for (int kc = 0; kc < 8; ++kc){                                           \
        const bf16x8 af = *(const bf16x8*)&AfYhL[((my*10+kc)*64 + l)*8];        \
        acc = mfma16(af, wfr[kc], acc);                                         \
      }                                                                         \
      { const bf16x8 af8 = *(const bf16x8*)&AfYhL[((my*10+8)*64 + l)*8];        \
        const bf16x8 af9 = *(const bf16x8*)&AfYhL[((my*10+9)*64 + l)*8];        \
        acc = mfma16(af8, uf0, acc); acc = mfma16(af9, uf1, acc); }             \
      *(float4*)&yrow[my*16 + 4*lh] = make_float4(acc[0],acc[1],acc[2],acc[3]); \
    } }

  #pragma unroll 1
  for (int s = 0; s < 8; ++s){
    const int t = ch*8 + s;
    // build u fragments
    bf16x8 uf0, uf1;
    {
      union { ushort_t us[8]; bf16x8 v; } cv;
      cv.us[0]=f2bf(ua.x); cv.us[1]=f2bf(ua.y); cv.us[2]=f2bf(ua.z); cv.us[3]=f2bf(ua.w);
      cv.us[4]=f2bf(ub.x); cv.us[5]=f2bf(ub.y); cv.us[6]=f2bf(ub.z); cv.us[7]=f2bf(ub.w);
      uf0 = cv.v;
      cv.us[0]=f2bf(uc.x); cv.us[1]=f2bf(uc.y); cv.us[2]=f2bf(uc.z); cv.us[3]=f2bf(uc.w);
      cv.us[4]=0; cv.us[5]=0; cv.us[6]=0; cv.us[7]=0;
      uf1 = cv.v;
    }
    if (s < 7){
      const float* Ut = Ucol + (size_t)(t+1)*TS;
      ua = *(const float4*)&Ut[4*lh]; ub = *(const float4*)&Ut[16+4*lh]; uc = *(const float4*)&Ut[32+4*lh];
    }
    // scan step (lam from LDS)
    #pragma unroll
    for (int it = 0; it < 16; ++it){
      const bf16x8 a0 = *(const bf16x8*)&LwsL[((it*2+0)*64 + l)*8];
      const bf16x8 a1 = *(const bf16x8*)&LwsL[((it*2+1)*64 + l)*8];
      const float4 lv = *(const float4*)&lamL[32*(it>>1) + 16*(it&1) + 4*lh];
      f32x4 acc = {0.f,0.f,0.f,0.f};
      acc = mfma16(a0, uf0, acc);
      acc = mfma16(a1, uf1, acc);
      const int e0 = 8*(it>>1) + 4*(it&1);
      w[e0+0] = lv.x*w[e0+0] + acc[0];
      w[e0+1] = lv.y*w[e0+1] + acc[1];
      w[e0+2] = lv.z*w[e0+2] + acc[2];
      w[e0+3] = lv.w*w[e0+3] + acc[3];
    }
    // pack w fragments
    bf16x8 wfr[8];
    #pragma unroll
    for (int kc = 0; kc < 8; ++kc){
      union { ushort_t us[8]; bf16x8 v; } cv;
      #pragma unroll
      for (int j = 0; j < 8; ++j) cv.us[j] = f2bf(w[8*kc + j]);
      wfr[kc] = cv.v;
    }
    // output GEMMs (h is block-uniform; literal HH keeps wfr indices compile-time)
    if (h == 0){
      ZLOOP(0);
      YLOOP(0, 3);
    } else {
      ZLOOP(1);
      YLOOP(48, 2);
    }
  }
#undef ZLOOP
#undef YLOOP
}

// ---------------- launcher ----------------
extern "C" void kernel_launch(void* const* d_in, const int* in_sizes, int n_in,
                              void* d_out, int out_size, void* d_ws, size_t ws_size,
                              hipStream_t stream){
  const float* z0  = (const float*)d_in[0];
  const float* dt  = (const float*)d_in[2];
  const float* U   = (const float*)d_in[3];
  const float* eig = (const float*)d_in[4];
  const float* V   = (const float*)d_in[5];
  const float* L   = (const float*)d_in[6];
  const float* C   = (const float*)d_in[7];
  const float* Dm  = (const float*)d_in[8];
  float* outZ = (float*)d_out;
  float* outY = outZ + (size_t)T_*B_*D_;

  char* ws = (char*)d_ws;
  float* Xa    = (float*)(ws + 0);        // later reused as VinvT
  float* Xb    = (float*)(ws + 262144);
  float* Tt    = (float*)(ws + 524288);
  float* Lw    = (float*)(ws + 786432);
  float* Cw    = (float*)(ws + 835584);
  float* lam   = (float*)(ws + 917504);
  float* dVd   = (float*)(ws + 918528);
  ushort_t* Af   = (ushort_t*)(ws + 919552);
  ushort_t* Lws  = (ushort_t*)(ws + 1134592);
  ushort_t* Wchk = (ushort_t*)(ws + 1167360);
  if (ws_size < 17944576u) return;

  k_init<<<256,256,0,stream>>>(V, eig, Xa, lam);
  // Newton-Schulz, 3 iters from X0 = 2I - V  -> Vinv = Xb
  k_mm_mul<<<256,256,0,stream>>>(V, Xa, Tt);
  k_mm_upd<<<256,256,0,stream>>>(Xa, Tt, Xb);
  k_mm_mul<<<256,256,0,stream>>>(V, Xb, Tt);
  k_mm_upd<<<256,256,0,stream>>>(Xb, Tt, Xa);
  k_mm_mul<<<256,256,0,stream>>>(V, Xa, Tt);
  k_mm_upd<<<256,256,0,stream>>>(Xa, Tt, Xb);
  k_prep1<<<592,256,0,stream>>>(Xb, V, L, C, dt, /*VinvT=*/Xa, Lw, Cw, dVd);
  k_prep2<<<288,256,0,stream>>>(z0, /*VinvT=*/Xa, Lw, Wchk, Lws);
  k_packA<<<210,64,0,stream>>>(V, Cw, Dm, dt, Af);
  k_scan<<<256,256,0,stream>>>(U, Lws, lam, Wchk);
  k_fused<<<1024,256,0,stream>>>(U, Af, Lws, lam, dVd, Wchk, outZ, outY);
}